// Round 1
// baseline (1140.797 us; speedup 1.0000x reference)
//
#include <hip/hip_runtime.h>
#include <hip/hip_bf16.h>

typedef __attribute__((ext_vector_type(8))) short short8;
typedef __attribute__((ext_vector_type(4))) float f32x4;
typedef unsigned short ushort_t;

static constexpr int Bc = 2, Sc = 2048, HIDc = 4096, Hc = 32;
static constexpr int NOPEc = 128, ROPEc = 64, VDc = 128, QHDc = 192;
static constexpr int QLRc = 1536, KVLRc = 512;

#define CDIV(a,b) (((a)+(b)-1)/(b))

__device__ __forceinline__ float bf2f(ushort_t u){
  union { unsigned u32; float f; } x; x.u32 = ((unsigned)u) << 16; return x.f;
}
__device__ __forceinline__ ushort_t f2bf(float f){
  union { float f; unsigned u32; } x; x.f = f;
  unsigned r = x.u32 + 0x7FFFu + ((x.u32 >> 16) & 1u);
  return (ushort_t)(r >> 16);
}
__device__ __forceinline__ void gload16(const void* g, void* l){
  __builtin_amdgcn_global_load_lds((const __attribute__((address_space(1))) void*)g,
                                   (__attribute__((address_space(3))) void*)l, 16, 0, 0);
}

// ---------------- f32 -> bf16 convert (vectorized, grid-stride) ----------------
__global__ __launch_bounds__(256)
void f32_to_bf16(const float* __restrict__ in, ushort_t* __restrict__ out, long long n){
  long long stride = (long long)gridDim.x * 256 * 4;
  for (long long i = ((long long)blockIdx.x*256 + threadIdx.x)*4; i < n; i += stride){
    float4 v = *(const float4*)(in + i);
    unsigned long long pk = (unsigned long long)f2bf(v.x)
                          | ((unsigned long long)f2bf(v.y) << 16)
                          | ((unsigned long long)f2bf(v.z) << 32)
                          | ((unsigned long long)f2bf(v.w) << 48);
    *(unsigned long long*)(out + i) = pk;
  }
}

// ---------------- GEMM: C[M,N] = A[M,K] * Bw[N,K]^T (bf16 in, f32 acc) ----------
// m97 structure: 128x128 tile, BK=32, 4 waves (2x2), global_load_lds width 16.
template<bool OUTBF>
__global__ __launch_bounds__(256)
void gemm_bt(const ushort_t* __restrict__ A, const ushort_t* __restrict__ Bw,
             void* __restrict__ Cp, int M, int N, int K, int lda)
{
  __shared__ __attribute__((aligned(16))) ushort_t As[4096];
  __shared__ __attribute__((aligned(16))) ushort_t Bs[4096];
  const int tid = threadIdx.x;
  const int lane = tid & 63;
  const int w = tid >> 6, wr = w >> 1, wc = w & 1;
  const int m0 = blockIdx.y * 128, n0 = blockIdx.x * 128;
  const int fr = lane & 15, kq = lane >> 4;

  f32x4 acc[4][4];
  #pragma unroll
  for (int i=0;i<4;i++)
    #pragma unroll
    for (int j=0;j<4;j++) acc[i][j] = (f32x4){0.f,0.f,0.f,0.f};

  const int sr = tid >> 2;
  const int scc = (tid & 3) * 8;
  const ushort_t* Ag0 = A + (size_t)(m0 + sr) * lda + scc;
  const ushort_t* Ag1 = A + (size_t)(m0 + 64 + sr) * lda + scc;
  const ushort_t* Bg0 = Bw + (size_t)(n0 + sr) * K + scc;
  const ushort_t* Bg1 = Bw + (size_t)(n0 + 64 + sr) * K + scc;
  ushort_t* Al0 = &As[tid*8];
  ushort_t* Al1 = &As[2048 + tid*8];
  ushort_t* Bl0 = &Bs[tid*8];
  ushort_t* Bl1 = &Bs[2048 + tid*8];

  for (int k0 = 0; k0 < K; k0 += 32) {
    gload16(Ag0 + k0, Al0);
    gload16(Ag1 + k0, Al1);
    gload16(Bg0 + k0, Bl0);
    gload16(Bg1 + k0, Bl1);
    __syncthreads();                      // vmcnt(0) drain -> LDS valid
    short8 a[4], b[4];
    #pragma unroll
    for (int m=0;m<4;m++) a[m] = *(const short8*)&As[(wr*64 + m*16 + fr)*32 + kq*8];
    #pragma unroll
    for (int n=0;n<4;n++) b[n] = *(const short8*)&Bs[(wc*64 + n*16 + fr)*32 + kq*8];
    #pragma unroll
    for (int m=0;m<4;m++)
      #pragma unroll
      for (int n=0;n<4;n++)
        acc[m][n] = __builtin_amdgcn_mfma_f32_16x16x32_bf16(a[m], b[n], acc[m][n], 0, 0, 0);
    __syncthreads();                      // protect LDS before next stage
  }

  const int rb = m0 + wr*64 + kq*4;
  const int cb = n0 + wc*64 + fr;
  #pragma unroll
  for (int m=0;m<4;m++)
    #pragma unroll
    for (int n=0;n<4;n++){
      int col = cb + n*16;
      if (col < N) {
        #pragma unroll
        for (int j=0;j<4;j++){
          int row = rb + m*16 + j;
          float v = acc[m][n][j];
          if (OUTBF) ((ushort_t*)Cp)[(size_t)row*N + col] = f2bf(v);
          else       ((float*)  Cp)[(size_t)row*N + col] = v;
        }
      }
    }
}

// ---------------- RMSNorm in-place on bf16 rows ----------------
__global__ __launch_bounds__(256)
void rmsnorm_ip(ushort_t* __restrict__ x, const float* __restrict__ w, int D, int rowstride){
  const int row = blockIdx.x;
  ushort_t* p = x + (size_t)row * rowstride;
  float ss = 0.f;
  for (int c = threadIdx.x*8; c < D; c += 2048) {
    short8 v = *(const short8*)(p + c);
    #pragma unroll
    for (int j=0;j<8;j++){ float f = bf2f((ushort_t)v[j]); ss += f*f; }
  }
  #pragma unroll
  for (int m=1;m<64;m<<=1) ss += __shfl_xor(ss, m, 64);
  __shared__ float red[4];
  if ((threadIdx.x & 63)==0) red[threadIdx.x>>6] = ss;
  __syncthreads();
  float tot = red[0]+red[1]+red[2]+red[3];
  float inv = rsqrtf(tot/(float)D + 1e-6f);
  for (int c = threadIdx.x*8; c < D; c += 2048) {
    short8 v = *(const short8*)(p + c);
    short8 o;
    #pragma unroll
    for (int j=0;j<8;j++) o[j] = (short)f2bf(bf2f((ushort_t)v[j]) * inv * w[c+j]);
    *(short8*)(p + c) = o;
  }
}

// ---------------- RoPE tables ----------------
__global__ void rope_tab(float* __restrict__ ct, float* __restrict__ st){
  int i = blockIdx.x*256 + threadIdx.x;
  if (i >= Sc*32) return;
  int t = i >> 5, p = i & 31;
  float invf = exp2f(-(float)p * (13.287712379549449f / 32.f)); // 10000^(-p/32)
  float ang = (float)t * invf;
  ct[i] = cosf(ang);
  st[i] = sinf(ang);
}

// RoPE on q_pe: pair (2p,2p+1) -> (a c - b s, b c + a s); layout consistent q/k
__global__ void rope_q(ushort_t* __restrict__ q, const float* __restrict__ ct, const float* __restrict__ st){
  int i = blockIdx.x*256 + threadIdx.x;
  if (i >= Bc*Sc*Hc*32) return;
  int p = i & 31, h = (i >> 5) & (Hc-1);
  int bs = i >> 10;
  int t = bs & (Sc-1);
  ushort_t* base = q + (size_t)bs*Hc*QHDc + h*QHDc + NOPEc + 2*p;
  unsigned u = *(const unsigned*)base;
  float a = bf2f((ushort_t)(u & 0xFFFFu)), bb = bf2f((ushort_t)(u >> 16));
  float c = ct[t*32+p], s = st[t*32+p];
  unsigned o = (unsigned)f2bf(a*c - bb*s) | ((unsigned)f2bf(bb*c + a*s) << 16);
  *(unsigned*)base = o;
}

__global__ void rope_k(ushort_t* __restrict__ ckv, const float* __restrict__ ct, const float* __restrict__ st){
  int i = blockIdx.x*256 + threadIdx.x;
  if (i >= Bc*Sc*32) return;
  int p = i & 31;
  int bs = i >> 5;
  int t = bs & (Sc-1);
  ushort_t* base = ckv + (size_t)bs*576 + 512 + 2*p;
  unsigned u = *(const unsigned*)base;
  float a = bf2f((ushort_t)(u & 0xFFFFu)), bb = bf2f((ushort_t)(u >> 16));
  float c = ct[t*32+p], s = st[t*32+p];
  unsigned o = (unsigned)f2bf(a*c - bb*s) | ((unsigned)f2bf(bb*c + a*s) << 16);
  *(unsigned*)base = o;
}

// ---------------- V transpose: kv[bs][h][256](+128) -> vt[bh][vd][s] ----------------
__global__ __launch_bounds__(256)
void vtrans(const ushort_t* __restrict__ kv, ushort_t* __restrict__ vt){
  const int s0 = blockIdx.x * 64;
  const int bh = blockIdx.y;
  const int batch = bh >> 5, h = bh & 31;
  __shared__ __attribute__((aligned(16))) ushort_t L[64][136];
  #pragma unroll
  for (int i = 0; i < 4; i++) {
    int chunk = i*256 + threadIdx.x;
    int r = chunk >> 4;
    int c = (chunk & 15) * 8;
    short8 v = *(const short8*)(kv + ((size_t)(batch*Sc + s0 + r)*Hc + h)*256 + 128 + c);
    *(short8*)&L[r][c] = v;
  }
  __syncthreads();
  #pragma unroll
  for (int i = 0; i < 4; i++) {
    int chunk = i*256 + threadIdx.x;
    int vd = chunk >> 3;
    int sc2 = (chunk & 7) * 8;
    short8 o;
    #pragma unroll
    for (int j=0;j<8;j++) o[j] = (short)L[sc2+j][vd];
    *(short8*)(vt + ((size_t)bh*VDc + vd)*Sc + s0 + sc2) = o;
  }
}

// ---------------- Flash attention (causal), 64 q-rows/block, 4 waves ----------------
__global__ __launch_bounds__(256)
void attn_fwd(const ushort_t* __restrict__ qb, const ushort_t* __restrict__ kvb,
              const ushort_t* __restrict__ ckv, const ushort_t* __restrict__ vt,
              ushort_t* __restrict__ out)
{
  constexpr int KP = 200, VP = 40;   // padded strides: 2-way-bank-conflict only
  __shared__ __attribute__((aligned(16))) ushort_t Ks[32*KP];
  __shared__ __attribute__((aligned(16))) ushort_t Vs[128*VP];
  __shared__ __attribute__((aligned(16))) ushort_t Ps[4][16*VP];
  const int tid = threadIdx.x, lane = tid & 63, w = tid >> 6;
  const int fr = lane & 15, kq = lane >> 4;
  const int q0 = blockIdx.x * 64;
  const int bh = blockIdx.y, batch = bh >> 5, h = bh & 31;

  // Q fragments in registers (rows q0 + w*16 + fr)
  const int qrow = q0 + w*16 + fr;
  const ushort_t* qptr = qb + ((size_t)(batch*Sc + qrow)*Hc + h)*QHDc;
  short8 qf[6];
  #pragma unroll
  for (int kk=0;kk<6;kk++) qf[kk] = *(const short8*)(qptr + kk*32 + kq*8);

  f32x4 acc_o[8];
  #pragma unroll
  for (int i=0;i<8;i++) acc_o[i] = (f32x4){0.f,0.f,0.f,0.f};
  float mrow[4] = {-3e38f,-3e38f,-3e38f,-3e38f};
  float lrow[4] = {0.f,0.f,0.f,0.f};
  const float scl = 0.07216878364870323f * 1.4426950408889634f; // 192^-0.5 * log2(e)

  const int ktiles = q0/32 + 2;
  const int ksr = tid >> 3, ksub = tid & 7;   // K staging: 32 rows x 24 chunks
  const int vvd = tid >> 1, vsub = tid & 1;   // V staging: 128 rows x 4 chunks

  for (int kt = 0; kt < ktiles; kt++) {
    const int j0 = kt*32;
    {
      const ushort_t* krow  = kvb + ((size_t)(batch*Sc + j0 + ksr)*Hc + h)*256;
      const ushort_t* perow = ckv + (size_t)(batch*Sc + j0 + ksr)*576 + 512;
      #pragma unroll
      for (int i=0;i<3;i++){
        int c = (ksub*3 + i)*8;
        short8 v = (c < 128) ? *(const short8*)(krow + c)
                             : *(const short8*)(perow + (c - 128));
        *(short8*)&Ks[ksr*KP + c] = v;
      }
      const ushort_t* vrow = vt + ((size_t)bh*VDc + vvd)*Sc + j0;
      #pragma unroll
      for (int i=0;i<2;i++){
        int c = (vsub*2 + i)*8;
        *(short8*)&Vs[vvd*VP + c] = *(const short8*)(vrow + c);
      }
    }
    __syncthreads();

    // scores: 16 q x 32 kv (two 16-col halves)
    f32x4 s0 = (f32x4){0.f,0.f,0.f,0.f}, s1 = (f32x4){0.f,0.f,0.f,0.f};
    #pragma unroll
    for (int kk=0;kk<6;kk++){
      short8 b0 = *(const short8*)&Ks[fr*KP + kk*32 + kq*8];
      short8 b1 = *(const short8*)&Ks[(16+fr)*KP + kk*32 + kq*8];
      s0 = __builtin_amdgcn_mfma_f32_16x16x32_bf16(qf[kk], b0, s0, 0,0,0);
      s1 = __builtin_amdgcn_mfma_f32_16x16x32_bf16(qf[kk], b1, s1, 0,0,0);
    }

    float x0[4], x1[4], tmax[4];
    #pragma unroll
    for (int j=0;j<4;j++){
      int qp = q0 + w*16 + kq*4 + j;
      float a  = s0[j]*scl, c2 = s1[j]*scl;
      if (j0 + fr      > qp) a  = -3e38f;
      if (j0 + 16 + fr > qp) c2 = -3e38f;
      x0[j] = a; x1[j] = c2;
      tmax[j] = fmaxf(a, c2);
    }
    #pragma unroll
    for (int m=1;m<16;m<<=1){
      #pragma unroll
      for (int j=0;j<4;j++) tmax[j] = fmaxf(tmax[j], __shfl_xor(tmax[j], m, 64));
    }
    float corr[4], rsum[4], p0[4], p1[4];
    #pragma unroll
    for (int j=0;j<4;j++){
      float mn = fmaxf(mrow[j], tmax[j]);
      corr[j] = exp2f(mrow[j] - mn);
      mrow[j] = mn;
      p0[j] = exp2f(x0[j] - mn);
      p1[j] = exp2f(x1[j] - mn);
      rsum[j] = p0[j] + p1[j];
    }
    #pragma unroll
    for (int m=1;m<16;m<<=1){
      #pragma unroll
      for (int j=0;j<4;j++) rsum[j] += __shfl_xor(rsum[j], m, 64);
    }
    #pragma unroll
    for (int j=0;j<4;j++) lrow[j] = lrow[j]*corr[j] + rsum[j];
    #pragma unroll
    for (int i=0;i<8;i++){
      #pragma unroll
      for (int j=0;j<4;j++) acc_o[i][j] *= corr[j];
    }
    // P -> per-wave LDS (layout [q][kv]) then A-fragment read
    #pragma unroll
    for (int j=0;j<4;j++){
      Ps[w][(kq*4+j)*VP + fr]      = f2bf(p0[j]);
      Ps[w][(kq*4+j)*VP + 16 + fr] = f2bf(p1[j]);
    }
    short8 ap = *(const short8*)&Ps[w][fr*VP + kq*8];
    #pragma unroll
    for (int v8=0; v8<8; v8++){
      short8 bv = *(const short8*)&Vs[(v8*16 + fr)*VP + kq*8];
      acc_o[v8] = __builtin_amdgcn_mfma_f32_16x16x32_bf16(ap, bv, acc_o[v8], 0,0,0);
    }
    __syncthreads();
  }

  #pragma unroll
  for (int v8=0; v8<8; v8++){
    #pragma unroll
    for (int j=0;j<4;j++){
      int qg = q0 + w*16 + kq*4 + j;
      float o = acc_o[v8][j] / lrow[j];
      out[(size_t)(batch*Sc + qg)*(Hc*VDc) + h*VDc + v8*16 + fr] = f2bf(o);
    }
  }
}

// ---------------- launcher ----------------
extern "C" void kernel_launch(void* const* d_in, const int* in_sizes, int n_in,
                              void* d_out, int out_size, void* d_ws, size_t ws_size,
                              hipStream_t stream) {
  (void)in_sizes; (void)n_in; (void)out_size; (void)ws_size;
  const float* hidden  = (const float*)d_in[0];
  // d_in[1] attention_mask (pure causal -> reproduced analytically)
  // d_in[2] position_ids   (arange -> pos == s)
  const float* q_a_w   = (const float*)d_in[3];
  const float* q_a_ln  = (const float*)d_in[4];
  const float* q_b_w   = (const float*)d_in[5];
  const float* kv_a_w  = (const float*)d_in[6];
  const float* kv_a_ln = (const float*)d_in[7];
  const float* kv_b_w  = (const float*)d_in[8];
  const float* o_w     = (const float*)d_in[9];
  float* outp = (float*)d_out;

  char* ws = (char*)d_ws;
  size_t off = 0;
  auto alloc = [&](size_t n)->char*{ char* p = ws + off; off += (n + 255) & ~(size_t)255; return p; };
  ushort_t* hbf  = (ushort_t*)alloc((size_t)Bc*Sc*HIDc*2);        // hidden bf16; later reused for o_w bf16
  ushort_t* wb   = (ushort_t*)alloc((size_t)Hc*QHDc*QLRc*2);      // weight staging (max = q_b_w); covers 640-row over-read
  ushort_t* qa   = (ushort_t*)alloc((size_t)Bc*Sc*QLRc*2);
  ushort_t* qbf  = (ushort_t*)alloc((size_t)Bc*Sc*Hc*QHDc*2);
  ushort_t* ckv  = (ushort_t*)alloc((size_t)Bc*Sc*576*2);
  ushort_t* kvbf = (ushort_t*)alloc((size_t)Bc*Sc*Hc*256*2);
  ushort_t* vtb  = (ushort_t*)alloc((size_t)Bc*Hc*VDc*Sc*2);
  ushort_t* aout = (ushort_t*)alloc((size_t)Bc*Sc*Hc*VDc*2);
  float*    ct   = (float*)alloc((size_t)Sc*32*4);
  float*    st   = (float*)alloc((size_t)Sc*32*4);

  const int M = Bc*Sc; // 4096

  f32_to_bf16<<<2048,256,0,stream>>>(hidden, hbf, (long long)M*HIDc);
  // q_a = rmsnorm(hidden @ q_a_w^T)
  f32_to_bf16<<<1024,256,0,stream>>>(q_a_w, wb, (long long)QLRc*HIDc);
  gemm_bt<true><<<dim3(QLRc/128, M/128),256,0,stream>>>(hbf, wb, qa, M, QLRc, HIDc, HIDc);
  rmsnorm_ip<<<M,256,0,stream>>>(qa, q_a_ln, QLRc, QLRc);
  // q = q_a @ q_b_w^T
  f32_to_bf16<<<1024,256,0,stream>>>(q_b_w, wb, (long long)Hc*QHDc*QLRc);
  gemm_bt<true><<<dim3(Hc*QHDc/128, M/128),256,0,stream>>>(qa, wb, qbf, M, Hc*QHDc, QLRc, QLRc);
  // ckv = hidden @ kv_a_w^T   (N=576 -> 5 col-tiles, store bounds-checked)
  f32_to_bf16<<<1024,256,0,stream>>>(kv_a_w, wb, (long long)(KVLRc+ROPEc)*HIDc);
  gemm_bt<true><<<dim3(5, M/128),256,0,stream>>>(hbf, wb, ckv, M, KVLRc+ROPEc, HIDc, HIDc);
  rmsnorm_ip<<<M,256,0,stream>>>(ckv, kv_a_ln, KVLRc, 576);
  // kv = ckv_norm @ kv_b_w^T  (A row-stride 576)
  f32_to_bf16<<<1024,256,0,stream>>>(kv_b_w, wb, (long long)Hc*256*KVLRc);
  gemm_bt<true><<<dim3(Hc*256/128, M/128),256,0,stream>>>(ckv, wb, kvbf, M, Hc*256, KVLRc, 576);
  // RoPE
  rope_tab<<<CDIV(Sc*32,256),256,0,stream>>>(ct, st);
  rope_q<<<CDIV(Bc*Sc*Hc*32,256),256,0,stream>>>(qbf, ct, st);
  rope_k<<<CDIV(Bc*Sc*32,256),256,0,stream>>>(ckv, ct, st);
  // V transpose + attention
  vtrans<<<dim3(Sc/64, Bc*Hc),256,0,stream>>>(kvbf, vtb);
  attn_fwd<<<dim3(Sc/64, Bc*Hc),256,0,stream>>>(qbf, kvbf, ckv, vtb, aout);
  // out = attn @ o_w^T  (f32 store)
  f32_to_bf16<<<2048,256,0,stream>>>(o_w, hbf, (long long)HIDc*HIDc);
  gemm_bt<false><<<dim3(HIDc/128, M/128),256,0,stream>>>(aout, hbf, outp, M, HIDc, HIDc, HIDc);
}

// Round 2
// 947.497 us; speedup vs baseline: 1.2040x; 1.2040x over previous
//
#include <hip/hip_runtime.h>
#include <hip/hip_bf16.h>

typedef __attribute__((ext_vector_type(8))) short short8;
typedef __attribute__((ext_vector_type(4))) float f32x4;
typedef unsigned short ushort_t;

static constexpr int Bc = 2, Sc = 2048, HIDc = 4096, Hc = 32;
static constexpr int NOPEc = 128, ROPEc = 64, VDc = 128, QHDc = 192;
static constexpr int QLRc = 1536, KVLRc = 512;

#define CDIV(a,b) (((a)+(b)-1)/(b))

__device__ __forceinline__ float bf2f(ushort_t u){
  union { unsigned u32; float f; } x; x.u32 = ((unsigned)u) << 16; return x.f;
}
__device__ __forceinline__ ushort_t f2bf(float f){
  union { float f; unsigned u32; } x; x.f = f;
  unsigned r = x.u32 + 0x7FFFu + ((x.u32 >> 16) & 1u);
  return (ushort_t)(r >> 16);
}
__device__ __forceinline__ void gload16(const void* g, void* l){
  __builtin_amdgcn_global_load_lds((const __attribute__((address_space(1))) void*)g,
                                   (__attribute__((address_space(3))) void*)l, 16, 0, 0);
}

// ---------------- f32 -> bf16 convert (vectorized, grid-stride) ----------------
__global__ __launch_bounds__(256)
void f32_to_bf16(const float* __restrict__ in, ushort_t* __restrict__ out, long long n){
  long long stride = (long long)gridDim.x * 256 * 4;
  for (long long i = ((long long)blockIdx.x*256 + threadIdx.x)*4; i < n; i += stride){
    float4 v = *(const float4*)(in + i);
    unsigned long long pk = (unsigned long long)f2bf(v.x)
                          | ((unsigned long long)f2bf(v.y) << 16)
                          | ((unsigned long long)f2bf(v.z) << 32)
                          | ((unsigned long long)f2bf(v.w) << 48);
    *(unsigned long long*)(out + i) = pk;
  }
}

// ---------------- GEMM: C[M,N] = A[M,K] * Bw[N,K]^T (bf16 in, f32 acc) ----------
// m97 structure: 128x128 tile, BK=32, 4 waves (2x2), global_load_lds width 16.
template<bool OUTBF>
__global__ __launch_bounds__(256)
void gemm_bt(const ushort_t* __restrict__ A, const ushort_t* __restrict__ Bw,
             void* __restrict__ Cp, int M, int N, int K, int lda)
{
  __shared__ __attribute__((aligned(16))) ushort_t As[4096];
  __shared__ __attribute__((aligned(16))) ushort_t Bs[4096];
  const int tid = threadIdx.x;
  const int lane = tid & 63;
  const int w = tid >> 6, wr = w >> 1, wc = w & 1;
  const int m0 = blockIdx.y * 128, n0 = blockIdx.x * 128;
  const int fr = lane & 15, kq = lane >> 4;

  f32x4 acc[4][4];
  #pragma unroll
  for (int i=0;i<4;i++)
    #pragma unroll
    for (int j=0;j<4;j++) acc[i][j] = (f32x4){0.f,0.f,0.f,0.f};

  const int sr = tid >> 2;
  const int scc = (tid & 3) * 8;
  const ushort_t* Ag0 = A + (size_t)(m0 + sr) * lda + scc;
  const ushort_t* Ag1 = A + (size_t)(m0 + 64 + sr) * lda + scc;
  const ushort_t* Bg0 = Bw + (size_t)(n0 + sr) * K + scc;
  const ushort_t* Bg1 = Bw + (size_t)(n0 + 64 + sr) * K + scc;
  ushort_t* Al0 = &As[tid*8];
  ushort_t* Al1 = &As[2048 + tid*8];
  ushort_t* Bl0 = &Bs[tid*8];
  ushort_t* Bl1 = &Bs[2048 + tid*8];

  for (int k0 = 0; k0 < K; k0 += 32) {
    gload16(Ag0 + k0, Al0);
    gload16(Ag1 + k0, Al1);
    gload16(Bg0 + k0, Bl0);
    gload16(Bg1 + k0, Bl1);
    __syncthreads();                      // vmcnt(0) drain -> LDS valid
    short8 a[4], b[4];
    #pragma unroll
    for (int m=0;m<4;m++) a[m] = *(const short8*)&As[(wr*64 + m*16 + fr)*32 + kq*8];
    #pragma unroll
    for (int n=0;n<4;n++) b[n] = *(const short8*)&Bs[(wc*64 + n*16 + fr)*32 + kq*8];
    #pragma unroll
    for (int m=0;m<4;m++)
      #pragma unroll
      for (int n=0;n<4;n++)
        acc[m][n] = __builtin_amdgcn_mfma_f32_16x16x32_bf16(a[m], b[n], acc[m][n], 0, 0, 0);
    __syncthreads();                      // protect LDS before next stage
  }

  const int rb = m0 + wr*64 + kq*4;
  const int cb = n0 + wc*64 + fr;
  #pragma unroll
  for (int m=0;m<4;m++)
    #pragma unroll
    for (int n=0;n<4;n++){
      int col = cb + n*16;
      if (col < N) {
        #pragma unroll
        for (int j=0;j<4;j++){
          int row = rb + m*16 + j;
          float v = acc[m][n][j];
          if (OUTBF) ((ushort_t*)Cp)[(size_t)row*N + col] = f2bf(v);
          else       ((float*)  Cp)[(size_t)row*N + col] = v;
        }
      }
    }
}

// ---------------- RMSNorm in-place on bf16 rows ----------------
__global__ __launch_bounds__(256)
void rmsnorm_ip(ushort_t* __restrict__ x, const float* __restrict__ w, int D, int rowstride){
  const int row = blockIdx.x;
  ushort_t* p = x + (size_t)row * rowstride;
  float ss = 0.f;
  for (int c = threadIdx.x*8; c < D; c += 2048) {
    short8 v = *(const short8*)(p + c);
    #pragma unroll
    for (int j=0;j<8;j++){ float f = bf2f((ushort_t)v[j]); ss += f*f; }
  }
  #pragma unroll
  for (int m=1;m<64;m<<=1) ss += __shfl_xor(ss, m, 64);
  __shared__ float red[4];
  if ((threadIdx.x & 63)==0) red[threadIdx.x>>6] = ss;
  __syncthreads();
  float tot = red[0]+red[1]+red[2]+red[3];
  float inv = rsqrtf(tot/(float)D + 1e-6f);
  for (int c = threadIdx.x*8; c < D; c += 2048) {
    short8 v = *(const short8*)(p + c);
    short8 o;
    #pragma unroll
    for (int j=0;j<8;j++) o[j] = (short)f2bf(bf2f((ushort_t)v[j]) * inv * w[c+j]);
    *(short8*)(p + c) = o;
  }
}

// ---------------- RoPE tables ----------------
__global__ void rope_tab(float* __restrict__ ct, float* __restrict__ st){
  int i = blockIdx.x*256 + threadIdx.x;
  if (i >= Sc*32) return;
  int t = i >> 5, p = i & 31;
  float invf = exp2f(-(float)p * (13.287712379549449f / 32.f)); // 10000^(-p/32)
  float ang = (float)t * invf;
  ct[i] = cosf(ang);
  st[i] = sinf(ang);
}

// RoPE on q_pe: pair (2p,2p+1) -> (a c - b s, b c + a s); layout consistent q/k
__global__ void rope_q(ushort_t* __restrict__ q, const float* __restrict__ ct, const float* __restrict__ st){
  int i = blockIdx.x*256 + threadIdx.x;
  if (i >= Bc*Sc*Hc*32) return;
  int p = i & 31, h = (i >> 5) & (Hc-1);
  int bs = i >> 10;
  int t = bs & (Sc-1);
  ushort_t* base = q + (size_t)bs*Hc*QHDc + h*QHDc + NOPEc + 2*p;
  unsigned u = *(const unsigned*)base;
  float a = bf2f((ushort_t)(u & 0xFFFFu)), bb = bf2f((ushort_t)(u >> 16));
  float c = ct[t*32+p], s = st[t*32+p];
  unsigned o = (unsigned)f2bf(a*c - bb*s) | ((unsigned)f2bf(bb*c + a*s) << 16);
  *(unsigned*)base = o;
}

__global__ void rope_k(ushort_t* __restrict__ ckv, const float* __restrict__ ct, const float* __restrict__ st){
  int i = blockIdx.x*256 + threadIdx.x;
  if (i >= Bc*Sc*32) return;
  int p = i & 31;
  int bs = i >> 5;
  int t = bs & (Sc-1);
  ushort_t* base = ckv + (size_t)bs*576 + 512 + 2*p;
  unsigned u = *(const unsigned*)base;
  float a = bf2f((ushort_t)(u & 0xFFFFu)), bb = bf2f((ushort_t)(u >> 16));
  float c = ct[t*32+p], s = st[t*32+p];
  unsigned o = (unsigned)f2bf(a*c - bb*s) | ((unsigned)f2bf(bb*c + a*s) << 16);
  *(unsigned*)base = o;
}

// ---------------- V transpose: kv[bs][h][256](+128) -> vt[bh][vd][s] ----------------
__global__ __launch_bounds__(256)
void vtrans(const ushort_t* __restrict__ kv, ushort_t* __restrict__ vt){
  const int s0 = blockIdx.x * 64;
  const int bh = blockIdx.y;
  const int batch = bh >> 5, h = bh & 31;
  __shared__ __attribute__((aligned(16))) ushort_t L[64][136];
  #pragma unroll
  for (int i = 0; i < 4; i++) {
    int chunk = i*256 + threadIdx.x;
    int r = chunk >> 4;
    int c = (chunk & 15) * 8;
    short8 v = *(const short8*)(kv + ((size_t)(batch*Sc + s0 + r)*Hc + h)*256 + 128 + c);
    *(short8*)&L[r][c] = v;
  }
  __syncthreads();
  #pragma unroll
  for (int i = 0; i < 4; i++) {
    int chunk = i*256 + threadIdx.x;
    int vd = chunk >> 3;
    int sc2 = (chunk & 7) * 8;
    short8 o;
    #pragma unroll
    for (int j=0;j<8;j++) o[j] = (short)L[sc2+j][vd];
    *(short8*)(vt + ((size_t)bh*VDc + vd)*Sc + s0 + sc2) = o;
  }
}

// ---------------- Flash attention (causal), 64 q-rows/block, 4 waves ----------------
// Grid: (x = bh [64], y = qtile [32], REVERSED) so round-robin dispatch gives each
// CU one bh (L2 KV reuse) and a balanced spread of causal depths.
__global__ __launch_bounds__(256)
void attn_fwd(const ushort_t* __restrict__ qb, const ushort_t* __restrict__ kvb,
              const ushort_t* __restrict__ ckv, const ushort_t* __restrict__ vt,
              ushort_t* __restrict__ out)
{
  constexpr int KP = 200, VP = 40;   // padded strides: 2-way-bank-conflict only
  __shared__ __attribute__((aligned(16))) ushort_t Ks[32*KP];
  __shared__ __attribute__((aligned(16))) ushort_t Vs[128*VP];
  __shared__ __attribute__((aligned(16))) ushort_t Ps[4][16*VP];
  const int tid = threadIdx.x, lane = tid & 63, w = tid >> 6;
  const int fr = lane & 15, kq = lane >> 4;
  const int qt = (int)gridDim.y - 1 - (int)blockIdx.y;   // long blocks first
  const int q0 = qt * 64;
  const int bh = blockIdx.x, batch = bh >> 5, h = bh & 31;

  // Q fragments in registers (rows q0 + w*16 + fr)
  const int qrow = q0 + w*16 + fr;
  const ushort_t* qptr = qb + ((size_t)(batch*Sc + qrow)*Hc + h)*QHDc;
  short8 qf[6];
  #pragma unroll
  for (int kk=0;kk<6;kk++) qf[kk] = *(const short8*)(qptr + kk*32 + kq*8);

  f32x4 acc_o[8];
  #pragma unroll
  for (int i=0;i<8;i++) acc_o[i] = (f32x4){0.f,0.f,0.f,0.f};
  float mrow[4] = {-3e38f,-3e38f,-3e38f,-3e38f};
  float lrow[4] = {0.f,0.f,0.f,0.f};
  const float scl = 0.07216878364870323f * 1.4426950408889634f; // 192^-0.5 * log2(e)

  const int ktiles = q0/32 + 2;
  const int ksr = tid >> 3, ksub = tid & 7;   // K staging: 32 rows x 24 chunks
  const int vvd = tid >> 1, vsub = tid & 1;   // V staging: 128 rows x 4 chunks

  // T14 async-STAGE: global->reg for tile kt+1 issued right after first barrier,
  // reg->LDS write happens at top of next iteration (latency hides under compute).
  short8 kreg[3], vreg[2];
  const ushort_t* kbase  = kvb + ((size_t)batch*Sc + ksr)*((size_t)Hc*256) + (size_t)h*256;
  const ushort_t* pebase = ckv + ((size_t)batch*Sc + ksr)*576 + 512;
  const ushort_t* vbase  = vt + ((size_t)bh*VDc + vvd)*Sc;

  {
    // prologue: loads for kt=0
    #pragma unroll
    for (int i=0;i<3;i++){
      int c = (ksub*3 + i)*8;
      kreg[i] = (c < 128) ? *(const short8*)(kbase + c)
                          : *(const short8*)(pebase + (c - 128));
    }
    #pragma unroll
    for (int i=0;i<2;i++) vreg[i] = *(const short8*)(vbase + (vsub*2+i)*8);
  }

  for (int kt = 0; kt < ktiles; kt++) {
    const int j0 = kt*32;
    // write staged regs to LDS
    #pragma unroll
    for (int i=0;i<3;i++) *(short8*)&Ks[ksr*KP + (ksub*3 + i)*8] = kreg[i];
    #pragma unroll
    for (int i=0;i<2;i++) *(short8*)&Vs[vvd*VP + (vsub*2 + i)*8] = vreg[i];
    __syncthreads();

    // issue next tile's global loads (overlap with compute below)
    if (kt + 1 < ktiles) {
      const size_t roff = (size_t)(j0 + 32);
      #pragma unroll
      for (int i=0;i<3;i++){
        int c = (ksub*3 + i)*8;
        kreg[i] = (c < 128) ? *(const short8*)(kbase + roff*((size_t)Hc*256) + c)
                            : *(const short8*)(pebase + roff*576 + (c - 128));
      }
      #pragma unroll
      for (int i=0;i<2;i++) vreg[i] = *(const short8*)(vbase + roff + (vsub*2+i)*8);
    }

    // scores: 16 q x 32 kv (two 16-col halves)
    f32x4 s0 = (f32x4){0.f,0.f,0.f,0.f}, s1 = (f32x4){0.f,0.f,0.f,0.f};
    #pragma unroll
    for (int kk=0;kk<6;kk++){
      short8 b0 = *(const short8*)&Ks[fr*KP + kk*32 + kq*8];
      short8 b1 = *(const short8*)&Ks[(16+fr)*KP + kk*32 + kq*8];
      s0 = __builtin_amdgcn_mfma_f32_16x16x32_bf16(qf[kk], b0, s0, 0,0,0);
      s1 = __builtin_amdgcn_mfma_f32_16x16x32_bf16(qf[kk], b1, s1, 0,0,0);
    }

    const bool full = (j0 + 31 <= q0 + w*16);   // wave-uniform: no masking needed
    float x0[4], x1[4], tmax[4];
    #pragma unroll
    for (int j=0;j<4;j++){
      float a  = s0[j]*scl, c2 = s1[j]*scl;
      if (!full) {
        int qp = q0 + w*16 + kq*4 + j;
        if (j0 + fr      > qp) a  = -3e38f;
        if (j0 + 16 + fr > qp) c2 = -3e38f;
      }
      x0[j] = a; x1[j] = c2;
      tmax[j] = fmaxf(a, c2);
    }
    #pragma unroll
    for (int m=1;m<16;m<<=1){
      #pragma unroll
      for (int j=0;j<4;j++) tmax[j] = fmaxf(tmax[j], __shfl_xor(tmax[j], m, 64));
    }
    float corr[4], rsum[4], p0[4], p1[4];
    #pragma unroll
    for (int j=0;j<4;j++){
      float mn = fmaxf(mrow[j], tmax[j]);
      corr[j] = exp2f(mrow[j] - mn);
      mrow[j] = mn;
      p0[j] = exp2f(x0[j] - mn);
      p1[j] = exp2f(x1[j] - mn);
      rsum[j] = p0[j] + p1[j];
    }
    #pragma unroll
    for (int m=1;m<16;m<<=1){
      #pragma unroll
      for (int j=0;j<4;j++) rsum[j] += __shfl_xor(rsum[j], m, 64);
    }
    #pragma unroll
    for (int j=0;j<4;j++) lrow[j] = lrow[j]*corr[j] + rsum[j];
    #pragma unroll
    for (int i=0;i<8;i++){
      #pragma unroll
      for (int j=0;j<4;j++) acc_o[i][j] *= corr[j];
    }
    // P -> per-wave LDS (layout [q][kv]) then A-fragment read
    #pragma unroll
    for (int j=0;j<4;j++){
      Ps[w][(kq*4+j)*VP + fr]      = f2bf(p0[j]);
      Ps[w][(kq*4+j)*VP + 16 + fr] = f2bf(p1[j]);
    }
    short8 ap = *(const short8*)&Ps[w][fr*VP + kq*8];
    #pragma unroll
    for (int v8=0; v8<8; v8++){
      short8 bv = *(const short8*)&Vs[(v8*16 + fr)*VP + kq*8];
      acc_o[v8] = __builtin_amdgcn_mfma_f32_16x16x32_bf16(ap, bv, acc_o[v8], 0,0,0);
    }
    __syncthreads();
  }

  #pragma unroll
  for (int v8=0; v8<8; v8++){
    #pragma unroll
    for (int j=0;j<4;j++){
      int qg = q0 + w*16 + kq*4 + j;
      float o = acc_o[v8][j] / lrow[j];
      out[(size_t)(batch*Sc + qg)*(Hc*VDc) + h*VDc + v8*16 + fr] = f2bf(o);
    }
  }
}

// ---------------- launcher ----------------
extern "C" void kernel_launch(void* const* d_in, const int* in_sizes, int n_in,
                              void* d_out, int out_size, void* d_ws, size_t ws_size,
                              hipStream_t stream) {
  (void)in_sizes; (void)n_in; (void)out_size; (void)ws_size;
  const float* hidden  = (const float*)d_in[0];
  // d_in[1] attention_mask (pure causal -> reproduced analytically)
  // d_in[2] position_ids   (arange -> pos == s)
  const float* q_a_w   = (const float*)d_in[3];
  const float* q_a_ln  = (const float*)d_in[4];
  const float* q_b_w   = (const float*)d_in[5];
  const float* kv_a_w  = (const float*)d_in[6];
  const float* kv_a_ln = (const float*)d_in[7];
  const float* kv_b_w  = (const float*)d_in[8];
  const float* o_w     = (const float*)d_in[9];
  float* outp = (float*)d_out;

  char* ws = (char*)d_ws;
  size_t off = 0;
  auto alloc = [&](size_t n)->char*{ char* p = ws + off; off += (n + 255) & ~(size_t)255; return p; };
  ushort_t* hbf  = (ushort_t*)alloc((size_t)Bc*Sc*HIDc*2);        // hidden bf16; later reused for o_w bf16
  ushort_t* wb   = (ushort_t*)alloc((size_t)Hc*QHDc*QLRc*2);      // weight staging (max = q_b_w); covers 640-row over-read
  ushort_t* qa   = (ushort_t*)alloc((size_t)Bc*Sc*QLRc*2);
  ushort_t* qbf  = (ushort_t*)alloc((size_t)Bc*Sc*Hc*QHDc*2);
  ushort_t* ckv  = (ushort_t*)alloc((size_t)Bc*Sc*576*2);
  ushort_t* kvbf = (ushort_t*)alloc((size_t)Bc*Sc*Hc*256*2);
  ushort_t* vtb  = (ushort_t*)alloc((size_t)Bc*Hc*VDc*Sc*2);
  ushort_t* aout = (ushort_t*)alloc((size_t)Bc*Sc*Hc*VDc*2);
  float*    ct   = (float*)alloc((size_t)Sc*32*4);
  float*    st   = (float*)alloc((size_t)Sc*32*4);

  const int M = Bc*Sc; // 4096

  f32_to_bf16<<<2048,256,0,stream>>>(hidden, hbf, (long long)M*HIDc);
  // q_a = rmsnorm(hidden @ q_a_w^T)
  f32_to_bf16<<<1024,256,0,stream>>>(q_a_w, wb, (long long)QLRc*HIDc);
  gemm_bt<true><<<dim3(QLRc/128, M/128),256,0,stream>>>(hbf, wb, qa, M, QLRc, HIDc, HIDc);
  rmsnorm_ip<<<M,256,0,stream>>>(qa, q_a_ln, QLRc, QLRc);
  // q = q_a @ q_b_w^T
  f32_to_bf16<<<1024,256,0,stream>>>(q_b_w, wb, (long long)Hc*QHDc*QLRc);
  gemm_bt<true><<<dim3(Hc*QHDc/128, M/128),256,0,stream>>>(qa, wb, qbf, M, Hc*QHDc, QLRc, QLRc);
  // ckv = hidden @ kv_a_w^T   (N=576 -> 5 col-tiles, store bounds-checked)
  f32_to_bf16<<<1024,256,0,stream>>>(kv_a_w, wb, (long long)(KVLRc+ROPEc)*HIDc);
  gemm_bt<true><<<dim3(5, M/128),256,0,stream>>>(hbf, wb, ckv, M, KVLRc+ROPEc, HIDc, HIDc);
  rmsnorm_ip<<<M,256,0,stream>>>(ckv, kv_a_ln, KVLRc, 576);
  // kv = ckv_norm @ kv_b_w^T  (A row-stride 576)
  f32_to_bf16<<<1024,256,0,stream>>>(kv_b_w, wb, (long long)Hc*256*KVLRc);
  gemm_bt<true><<<dim3(Hc*256/128, M/128),256,0,stream>>>(ckv, wb, kvbf, M, Hc*256, KVLRc, 576);
  // RoPE
  rope_tab<<<CDIV(Sc*32,256),256,0,stream>>>(ct, st);
  rope_q<<<CDIV(Bc*Sc*Hc*32,256),256,0,stream>>>(qbf, ct, st);
  rope_k<<<CDIV(Bc*Sc*32,256),256,0,stream>>>(ckv, ct, st);
  // V transpose + attention (grid: x=bh for balance + L2 reuse, y=qtile reversed)
  vtrans<<<dim3(Sc/64, Bc*Hc),256,0,stream>>>(kvbf, vtb);
  attn_fwd<<<dim3(Bc*Hc, Sc/64),256,0,stream>>>(qbf, kvbf, ckv, vtb, aout);
  // out = attn @ o_w^T  (f32 store)
  f32_to_bf16<<<2048,256,0,stream>>>(o_w, hbf, (long long)HIDc*HIDc);
  gemm_bt<false><<<dim3(HIDc/128, M/128),256,0,stream>>>(aout, hbf, outp, M, HIDc, HIDc, HIDc);
}

// Round 3
// 870.762 us; speedup vs baseline: 1.3101x; 1.0881x over previous
//
#include <hip/hip_runtime.h>
#include <hip/hip_bf16.h>

typedef __attribute__((ext_vector_type(8))) short short8;
typedef __attribute__((ext_vector_type(4))) float f32x4;
typedef unsigned short ushort_t;

static constexpr int Bc = 2, Sc = 2048, HIDc = 4096, Hc = 32;
static constexpr int NOPEc = 128, ROPEc = 64, VDc = 128, QHDc = 192;
static constexpr int QLRc = 1536, KVLRc = 512;

#define CDIV(a,b) (((a)+(b)-1)/(b))

__device__ __forceinline__ float bf2f(ushort_t u){
  union { unsigned u32; float f; } x; x.u32 = ((unsigned)u) << 16; return x.f;
}
__device__ __forceinline__ ushort_t f2bf(float f){
  union { float f; unsigned u32; } x; x.f = f;
  unsigned r = x.u32 + 0x7FFFu + ((x.u32 >> 16) & 1u);
  return (ushort_t)(r >> 16);
}
__device__ __forceinline__ void gload16(const void* g, void* l){
  __builtin_amdgcn_global_load_lds((const __attribute__((address_space(1))) void*)g,
                                   (__attribute__((address_space(3))) void*)l, 16, 0, 0);
}

// ---------------- f32 -> bf16 convert (vectorized, grid-stride) ----------------
__global__ __launch_bounds__(256)
void f32_to_bf16(const float* __restrict__ in, ushort_t* __restrict__ out, long long n){
  long long stride = (long long)gridDim.x * 256 * 4;
  for (long long i = ((long long)blockIdx.x*256 + threadIdx.x)*4; i < n; i += stride){
    float4 v = *(const float4*)(in + i);
    unsigned long long pk = (unsigned long long)f2bf(v.x)
                          | ((unsigned long long)f2bf(v.y) << 16)
                          | ((unsigned long long)f2bf(v.z) << 32)
                          | ((unsigned long long)f2bf(v.w) << 48);
    *(unsigned long long*)(out + i) = pk;
  }
}

// ---------------- GEMM: C[M,N] = A[M,K] * Bw[N,K]^T (bf16 in, f32 acc) ----------
// m97 structure: 128x128 tile, BK=32, 4 waves (2x2), global_load_lds width 16.
template<bool OUTBF>
__global__ __launch_bounds__(256)
void gemm_bt(const ushort_t* __restrict__ A, const ushort_t* __restrict__ Bw,
             void* __restrict__ Cp, int M, int N, int K, int lda)
{
  __shared__ __attribute__((aligned(16))) ushort_t As[4096];
  __shared__ __attribute__((aligned(16))) ushort_t Bs[4096];
  const int tid = threadIdx.x;
  const int lane = tid & 63;
  const int w = tid >> 6, wr = w >> 1, wc = w & 1;
  const int m0 = blockIdx.y * 128, n0 = blockIdx.x * 128;
  const int fr = lane & 15, kq = lane >> 4;

  f32x4 acc[4][4];
  #pragma unroll
  for (int i=0;i<4;i++)
    #pragma unroll
    for (int j=0;j<4;j++) acc[i][j] = (f32x4){0.f,0.f,0.f,0.f};

  const int sr = tid >> 2;
  const int scc = (tid & 3) * 8;
  const ushort_t* Ag0 = A + (size_t)(m0 + sr) * lda + scc;
  const ushort_t* Ag1 = A + (size_t)(m0 + 64 + sr) * lda + scc;
  const ushort_t* Bg0 = Bw + (size_t)(n0 + sr) * K + scc;
  const ushort_t* Bg1 = Bw + (size_t)(n0 + 64 + sr) * K + scc;
  ushort_t* Al0 = &As[tid*8];
  ushort_t* Al1 = &As[2048 + tid*8];
  ushort_t* Bl0 = &Bs[tid*8];
  ushort_t* Bl1 = &Bs[2048 + tid*8];

  for (int k0 = 0; k0 < K; k0 += 32) {
    gload16(Ag0 + k0, Al0);
    gload16(Ag1 + k0, Al1);
    gload16(Bg0 + k0, Bl0);
    gload16(Bg1 + k0, Bl1);
    __syncthreads();                      // vmcnt(0) drain -> LDS valid
    short8 a[4], b[4];
    #pragma unroll
    for (int m=0;m<4;m++) a[m] = *(const short8*)&As[(wr*64 + m*16 + fr)*32 + kq*8];
    #pragma unroll
    for (int n=0;n<4;n++) b[n] = *(const short8*)&Bs[(wc*64 + n*16 + fr)*32 + kq*8];
    #pragma unroll
    for (int m=0;m<4;m++)
      #pragma unroll
      for (int n=0;n<4;n++)
        acc[m][n] = __builtin_amdgcn_mfma_f32_16x16x32_bf16(a[m], b[n], acc[m][n], 0, 0, 0);
    __syncthreads();                      // protect LDS before next stage
  }

  const int rb = m0 + wr*64 + kq*4;
  const int cb = n0 + wc*64 + fr;
  #pragma unroll
  for (int m=0;m<4;m++)
    #pragma unroll
    for (int n=0;n<4;n++){
      int col = cb + n*16;
      if (col < N) {
        #pragma unroll
        for (int j=0;j<4;j++){
          int row = rb + m*16 + j;
          float v = acc[m][n][j];
          if (OUTBF) ((ushort_t*)Cp)[(size_t)row*N + col] = f2bf(v);
          else       ((float*)  Cp)[(size_t)row*N + col] = v;
        }
      }
    }
}

// ---------------- RMSNorm in-place on bf16 rows ----------------
__global__ __launch_bounds__(256)
void rmsnorm_ip(ushort_t* __restrict__ x, const float* __restrict__ w, int D, int rowstride){
  const int row = blockIdx.x;
  ushort_t* p = x + (size_t)row * rowstride;
  float ss = 0.f;
  for (int c = threadIdx.x*8; c < D; c += 2048) {
    short8 v = *(const short8*)(p + c);
    #pragma unroll
    for (int j=0;j<8;j++){ float f = bf2f((ushort_t)v[j]); ss += f*f; }
  }
  #pragma unroll
  for (int m=1;m<64;m<<=1) ss += __shfl_xor(ss, m, 64);
  __shared__ float red[4];
  if ((threadIdx.x & 63)==0) red[threadIdx.x>>6] = ss;
  __syncthreads();
  float tot = red[0]+red[1]+red[2]+red[3];
  float inv = rsqrtf(tot/(float)D + 1e-6f);
  for (int c = threadIdx.x*8; c < D; c += 2048) {
    short8 v = *(const short8*)(p + c);
    short8 o;
    #pragma unroll
    for (int j=0;j<8;j++) o[j] = (short)f2bf(bf2f((ushort_t)v[j]) * inv * w[c+j]);
    *(short8*)(p + c) = o;
  }
}

// ---------------- RoPE tables ----------------
__global__ void rope_tab(float* __restrict__ ct, float* __restrict__ st){
  int i = blockIdx.x*256 + threadIdx.x;
  if (i >= Sc*32) return;
  int t = i >> 5, p = i & 31;
  float invf = exp2f(-(float)p * (13.287712379549449f / 32.f)); // 10000^(-p/32)
  float ang = (float)t * invf;
  ct[i] = cosf(ang);
  st[i] = sinf(ang);
}

// RoPE on q_pe: pair (2p,2p+1) -> (a c - b s, b c + a s); layout consistent q/k
__global__ void rope_q(ushort_t* __restrict__ q, const float* __restrict__ ct, const float* __restrict__ st){
  int i = blockIdx.x*256 + threadIdx.x;
  if (i >= Bc*Sc*Hc*32) return;
  int p = i & 31, h = (i >> 5) & (Hc-1);
  int bs = i >> 10;
  int t = bs & (Sc-1);
  ushort_t* base = q + (size_t)bs*Hc*QHDc + h*QHDc + NOPEc + 2*p;
  unsigned u = *(const unsigned*)base;
  float a = bf2f((ushort_t)(u & 0xFFFFu)), bb = bf2f((ushort_t)(u >> 16));
  float c = ct[t*32+p], s = st[t*32+p];
  unsigned o = (unsigned)f2bf(a*c - bb*s) | ((unsigned)f2bf(bb*c + a*s) << 16);
  *(unsigned*)base = o;
}

__global__ void rope_k(ushort_t* __restrict__ ckv, const float* __restrict__ ct, const float* __restrict__ st){
  int i = blockIdx.x*256 + threadIdx.x;
  if (i >= Bc*Sc*32) return;
  int p = i & 31;
  int bs = i >> 5;
  int t = bs & (Sc-1);
  ushort_t* base = ckv + (size_t)bs*576 + 512 + 2*p;
  unsigned u = *(const unsigned*)base;
  float a = bf2f((ushort_t)(u & 0xFFFFu)), bb = bf2f((ushort_t)(u >> 16));
  float c = ct[t*32+p], s = st[t*32+p];
  unsigned o = (unsigned)f2bf(a*c - bb*s) | ((unsigned)f2bf(bb*c + a*s) << 16);
  *(unsigned*)base = o;
}

// ---------------- V transpose: kv[bs][h][256](+128) -> vt[bh][vd][s] ----------------
__global__ __launch_bounds__(256)
void vtrans(const ushort_t* __restrict__ kv, ushort_t* __restrict__ vt){
  const int s0 = blockIdx.x * 64;
  const int bh = blockIdx.y;
  const int batch = bh >> 5, h = bh & 31;
  __shared__ __attribute__((aligned(16))) ushort_t L[64][136];
  #pragma unroll
  for (int i = 0; i < 4; i++) {
    int chunk = i*256 + threadIdx.x;
    int r = chunk >> 4;
    int c = (chunk & 15) * 8;
    short8 v = *(const short8*)(kv + ((size_t)(batch*Sc + s0 + r)*Hc + h)*256 + 128 + c);
    *(short8*)&L[r][c] = v;
  }
  __syncthreads();
  #pragma unroll
  for (int i = 0; i < 4; i++) {
    int chunk = i*256 + threadIdx.x;
    int vd = chunk >> 3;
    int sc2 = (chunk & 7) * 8;
    short8 o;
    #pragma unroll
    for (int j=0;j<8;j++) o[j] = (short)L[sc2+j][vd];
    *(short8*)(vt + ((size_t)bh*VDc + vd)*Sc + s0 + sc2) = o;
  }
}

// ---------------- Flash attention (causal), 64 q-rows/block, 4 waves ----------------
// Grid: (x = bh [64], y = qtile [32], REVERSED). Softmax is reduction-free in the
// common path: deferred-max (speculative exp with stale row max, THR=8 in exp2
// domain) + deferred-sum (per-lane partials, one epilogue reduce).
__global__ __launch_bounds__(256)
void attn_fwd(const ushort_t* __restrict__ qb, const ushort_t* __restrict__ kvb,
              const ushort_t* __restrict__ ckv, const ushort_t* __restrict__ vt,
              ushort_t* __restrict__ out)
{
  constexpr int KP = 200, VP = 40;   // padded strides: 2-way-bank-conflict only
  __shared__ __attribute__((aligned(16))) ushort_t Ks[32*KP];
  __shared__ __attribute__((aligned(16))) ushort_t Vs[128*VP];
  __shared__ __attribute__((aligned(16))) ushort_t Ps[4][16*VP];
  const int tid = threadIdx.x, lane = tid & 63, w = tid >> 6;
  const int fr = lane & 15, kq = lane >> 4;
  const int qt = (int)gridDim.y - 1 - (int)blockIdx.y;   // long blocks first
  const int q0 = qt * 64;
  const int bh = blockIdx.x, batch = bh >> 5, h = bh & 31;

  // Q fragments in registers (rows q0 + w*16 + fr)
  const int qrow = q0 + w*16 + fr;
  const ushort_t* qptr = qb + ((size_t)(batch*Sc + qrow)*Hc + h)*QHDc;
  short8 qf[6];
  #pragma unroll
  for (int kk=0;kk<6;kk++) qf[kk] = *(const short8*)(qptr + kk*32 + kq*8);

  f32x4 acc_o[8];
  #pragma unroll
  for (int i=0;i<8;i++) acc_o[i] = (f32x4){0.f,0.f,0.f,0.f};
  float mrow[4]  = {-3e38f,-3e38f,-3e38f,-3e38f};
  float lpart[4] = {0.f,0.f,0.f,0.f};          // per-lane partial row sums
  const float scl = 0.07216878364870323f * 1.4426950408889634f; // 192^-0.5 * log2(e)
  const float THR = 8.0f;                       // defer-max threshold (exp2 domain)

  const int ktiles = q0/32 + 2;
  const int ksr = tid >> 3, ksub = tid & 7;   // K staging: 32 rows x 24 chunks
  const int vvd = tid >> 1, vsub = tid & 1;   // V staging: 128 rows x 4 chunks

  // T14 async-STAGE: global->reg for tile kt+1 issued right after first barrier,
  // reg->LDS write happens at top of next iteration (latency hides under compute).
  short8 kreg[3], vreg[2];
  const ushort_t* kbase  = kvb + ((size_t)batch*Sc + ksr)*((size_t)Hc*256) + (size_t)h*256;
  const ushort_t* pebase = ckv + ((size_t)batch*Sc + ksr)*576 + 512;
  const ushort_t* vbase  = vt + ((size_t)bh*VDc + vvd)*Sc;

  {
    // prologue: loads for kt=0
    #pragma unroll
    for (int i=0;i<3;i++){
      int c = (ksub*3 + i)*8;
      kreg[i] = (c < 128) ? *(const short8*)(kbase + c)
                          : *(const short8*)(pebase + (c - 128));
    }
    #pragma unroll
    for (int i=0;i<2;i++) vreg[i] = *(const short8*)(vbase + (vsub*2+i)*8);
  }

  for (int kt = 0; kt < ktiles; kt++) {
    const int j0 = kt*32;
    // write staged regs to LDS
    #pragma unroll
    for (int i=0;i<3;i++) *(short8*)&Ks[ksr*KP + (ksub*3 + i)*8] = kreg[i];
    #pragma unroll
    for (int i=0;i<2;i++) *(short8*)&Vs[vvd*VP + (vsub*2 + i)*8] = vreg[i];
    __syncthreads();

    // issue next tile's global loads (overlap with compute below)
    if (kt + 1 < ktiles) {
      const size_t roff = (size_t)(j0 + 32);
      #pragma unroll
      for (int i=0;i<3;i++){
        int c = (ksub*3 + i)*8;
        kreg[i] = (c < 128) ? *(const short8*)(kbase + roff*((size_t)Hc*256) + c)
                            : *(const short8*)(pebase + roff*576 + (c - 128));
      }
      #pragma unroll
      for (int i=0;i<2;i++) vreg[i] = *(const short8*)(vbase + roff + (vsub*2+i)*8);
    }

    // scores: 16 q x 32 kv (two 16-col halves)
    f32x4 s0 = (f32x4){0.f,0.f,0.f,0.f}, s1 = (f32x4){0.f,0.f,0.f,0.f};
    #pragma unroll
    for (int kk=0;kk<6;kk++){
      short8 b0 = *(const short8*)&Ks[fr*KP + kk*32 + kq*8];
      short8 b1 = *(const short8*)&Ks[(16+fr)*KP + kk*32 + kq*8];
      s0 = __builtin_amdgcn_mfma_f32_16x16x32_bf16(qf[kk], b0, s0, 0,0,0);
      s1 = __builtin_amdgcn_mfma_f32_16x16x32_bf16(qf[kk], b1, s1, 0,0,0);
    }

    const bool full = (j0 + 31 <= q0 + w*16);   // wave-uniform: no masking needed
    float x0[4], x1[4];
    int okl = 1;
    #pragma unroll
    for (int j=0;j<4;j++){
      float a  = s0[j]*scl, c2 = s1[j]*scl;
      if (!full) {
        int qp = q0 + w*16 + kq*4 + j;
        if (j0 + fr      > qp) a  = -3e38f;
        if (j0 + 16 + fr > qp) c2 = -3e38f;
      }
      x0[j] = a; x1[j] = c2;
      okl &= (fmaxf(a, c2) <= mrow[j] + THR) ? 1 : 0;
    }
    if (!__all(okl)) {
      // slow path (rare, ~first tile only): full max reduce + rescale
      float tmax[4];
      #pragma unroll
      for (int j=0;j<4;j++) tmax[j] = fmaxf(x0[j], x1[j]);
      #pragma unroll
      for (int m=1;m<16;m<<=1){
        #pragma unroll
        for (int j=0;j<4;j++) tmax[j] = fmaxf(tmax[j], __shfl_xor(tmax[j], m, 64));
      }
      #pragma unroll
      for (int j=0;j<4;j++){
        float mn = fmaxf(mrow[j], tmax[j]);
        float corr = exp2f(mrow[j] - mn);
        mrow[j] = mn;
        lpart[j] *= corr;
        #pragma unroll
        for (int i=0;i<8;i++) acc_o[i][j] *= corr;
      }
    }
    float p0[4], p1[4];
    #pragma unroll
    for (int j=0;j<4;j++){
      p0[j] = exp2f(x0[j] - mrow[j]);
      p1[j] = exp2f(x1[j] - mrow[j]);
      lpart[j] += p0[j] + p1[j];
    }
    // P -> per-wave LDS (layout [q][kv]) via packed bf16 convert
    #pragma unroll
    for (int j=0;j<4;j++){
      unsigned pk;
      asm("v_cvt_pk_bf16_f32 %0, %1, %2" : "=v"(pk) : "v"(p0[j]), "v"(p1[j]));
      Ps[w][(kq*4+j)*VP + fr]      = (ushort_t)(pk & 0xFFFFu);
      Ps[w][(kq*4+j)*VP + 16 + fr] = (ushort_t)(pk >> 16);
    }
    short8 ap = *(const short8*)&Ps[w][fr*VP + kq*8];
    #pragma unroll
    for (int v8=0; v8<8; v8++){
      short8 bv = *(const short8*)&Vs[(v8*16 + fr)*VP + kq*8];
      acc_o[v8] = __builtin_amdgcn_mfma_f32_16x16x32_bf16(ap, bv, acc_o[v8], 0,0,0);
    }
    __syncthreads();
  }

  // epilogue: one cross-lane sum reduce for the row denominators
  #pragma unroll
  for (int m=1;m<16;m<<=1){
    #pragma unroll
    for (int j=0;j<4;j++) lpart[j] += __shfl_xor(lpart[j], m, 64);
  }
  #pragma unroll
  for (int v8=0; v8<8; v8++){
    #pragma unroll
    for (int j=0;j<4;j++){
      int qg = q0 + w*16 + kq*4 + j;
      float o = acc_o[v8][j] / lpart[j];
      out[(size_t)(batch*Sc + qg)*(Hc*VDc) + h*VDc + v8*16 + fr] = f2bf(o);
    }
  }
}

// ---------------- launcher ----------------
extern "C" void kernel_launch(void* const* d_in, const int* in_sizes, int n_in,
                              void* d_out, int out_size, void* d_ws, size_t ws_size,
                              hipStream_t stream) {
  (void)in_sizes; (void)n_in; (void)out_size; (void)ws_size;
  const float* hidden  = (const float*)d_in[0];
  // d_in[1] attention_mask (pure causal -> reproduced analytically)
  // d_in[2] position_ids   (arange -> pos == s)
  const float* q_a_w   = (const float*)d_in[3];
  const float* q_a_ln  = (const float*)d_in[4];
  const float* q_b_w   = (const float*)d_in[5];
  const float* kv_a_w  = (const float*)d_in[6];
  const float* kv_a_ln = (const float*)d_in[7];
  const float* kv_b_w  = (const float*)d_in[8];
  const float* o_w     = (const float*)d_in[9];
  float* outp = (float*)d_out;

  char* ws = (char*)d_ws;
  size_t off = 0;
  auto alloc = [&](size_t n)->char*{ char* p = ws + off; off += (n + 255) & ~(size_t)255; return p; };
  ushort_t* hbf  = (ushort_t*)alloc((size_t)Bc*Sc*HIDc*2);        // hidden bf16; later reused for o_w bf16
  ushort_t* wb   = (ushort_t*)alloc((size_t)Hc*QHDc*QLRc*2);      // weight staging (max = q_b_w); covers 640-row over-read
  ushort_t* qa   = (ushort_t*)alloc((size_t)Bc*Sc*QLRc*2);
  ushort_t* qbf  = (ushort_t*)alloc((size_t)Bc*Sc*Hc*QHDc*2);
  ushort_t* ckv  = (ushort_t*)alloc((size_t)Bc*Sc*576*2);
  ushort_t* kvbf = (ushort_t*)alloc((size_t)Bc*Sc*Hc*256*2);
  ushort_t* vtb  = (ushort_t*)alloc((size_t)Bc*Hc*VDc*Sc*2);
  ushort_t* aout = (ushort_t*)alloc((size_t)Bc*Sc*Hc*VDc*2);
  float*    ct   = (float*)alloc((size_t)Sc*32*4);
  float*    st   = (float*)alloc((size_t)Sc*32*4);

  const int M = Bc*Sc; // 4096

  f32_to_bf16<<<2048,256,0,stream>>>(hidden, hbf, (long long)M*HIDc);
  // q_a = rmsnorm(hidden @ q_a_w^T)
  f32_to_bf16<<<1024,256,0,stream>>>(q_a_w, wb, (long long)QLRc*HIDc);
  gemm_bt<true><<<dim3(QLRc/128, M/128),256,0,stream>>>(hbf, wb, qa, M, QLRc, HIDc, HIDc);
  rmsnorm_ip<<<M,256,0,stream>>>(qa, q_a_ln, QLRc, QLRc);
  // q = q_a @ q_b_w^T
  f32_to_bf16<<<1024,256,0,stream>>>(q_b_w, wb, (long long)Hc*QHDc*QLRc);
  gemm_bt<true><<<dim3(Hc*QHDc/128, M/128),256,0,stream>>>(qa, wb, qbf, M, Hc*QHDc, QLRc, QLRc);
  // ckv = hidden @ kv_a_w^T   (N=576 -> 5 col-tiles, store bounds-checked)
  f32_to_bf16<<<1024,256,0,stream>>>(kv_a_w, wb, (long long)(KVLRc+ROPEc)*HIDc);
  gemm_bt<true><<<dim3(5, M/128),256,0,stream>>>(hbf, wb, ckv, M, KVLRc+ROPEc, HIDc, HIDc);
  rmsnorm_ip<<<M,256,0,stream>>>(ckv, kv_a_ln, KVLRc, 576);
  // kv = ckv_norm @ kv_b_w^T  (A row-stride 576)
  f32_to_bf16<<<1024,256,0,stream>>>(kv_b_w, wb, (long long)Hc*256*KVLRc);
  gemm_bt<true><<<dim3(Hc*256/128, M/128),256,0,stream>>>(ckv, wb, kvbf, M, Hc*256, KVLRc, 576);
  // RoPE
  rope_tab<<<CDIV(Sc*32,256),256,0,stream>>>(ct, st);
  rope_q<<<CDIV(Bc*Sc*Hc*32,256),256,0,stream>>>(qbf, ct, st);
  rope_k<<<CDIV(Bc*Sc*32,256),256,0,stream>>>(ckv, ct, st);
  // V transpose + attention (grid: x=bh for balance + L2 reuse, y=qtile reversed)
  vtrans<<<dim3(Sc/64, Bc*Hc),256,0,stream>>>(kvbf, vtb);
  attn_fwd<<<dim3(Bc*Hc, Sc/64),256,0,stream>>>(qbf, kvbf, ckv, vtb, aout);
  // out = attn @ o_w^T  (f32 store)
  f32_to_bf16<<<2048,256,0,stream>>>(o_w, hbf, (long long)HIDc*HIDc);
  gemm_bt<false><<<dim3(HIDc/128, M/128),256,0,stream>>>(aout, hbf, outp, M, HIDc, HIDc, HIDc);
}

// Round 4
// 761.608 us; speedup vs baseline: 1.4979x; 1.1433x over previous
//
#include <hip/hip_runtime.h>
#include <hip/hip_bf16.h>

typedef __attribute__((ext_vector_type(8))) short short8;
typedef __attribute__((ext_vector_type(4))) float f32x4;
typedef unsigned short ushort_t;

static constexpr int Bc = 2, Sc = 2048, HIDc = 4096, Hc = 32;
static constexpr int NOPEc = 128, ROPEc = 64, VDc = 128, QHDc = 192;
static constexpr int QLRc = 1536, KVLRc = 512;

#define CDIV(a,b) (((a)+(b)-1)/(b))

__device__ __forceinline__ float bf2f(ushort_t u){
  union { unsigned u32; float f; } x; x.u32 = ((unsigned)u) << 16; return x.f;
}
__device__ __forceinline__ ushort_t f2bf(float f){
  union { float f; unsigned u32; } x; x.f = f;
  unsigned r = x.u32 + 0x7FFFu + ((x.u32 >> 16) & 1u);
  return (ushort_t)(r >> 16);
}
__device__ __forceinline__ void gload16(const void* g, void* l){
  __builtin_amdgcn_global_load_lds((const __attribute__((address_space(1))) void*)g,
                                   (__attribute__((address_space(3))) void*)l, 16, 0, 0);
}

// ---------------- f32 -> bf16 convert (vectorized, grid-stride) ----------------
__global__ __launch_bounds__(256)
void f32_to_bf16(const float* __restrict__ in, ushort_t* __restrict__ out, long long n){
  long long stride = (long long)gridDim.x * 256 * 4;
  for (long long i = ((long long)blockIdx.x*256 + threadIdx.x)*4; i < n; i += stride){
    float4 v = *(const float4*)(in + i);
    unsigned long long pk = (unsigned long long)f2bf(v.x)
                          | ((unsigned long long)f2bf(v.y) << 16)
                          | ((unsigned long long)f2bf(v.z) << 32)
                          | ((unsigned long long)f2bf(v.w) << 48);
    *(unsigned long long*)(out + i) = pk;
  }
}

// ======== GEMM 256x256 tile, BK=64, 8 waves, dbuf LDS, swizzled, counted vmcnt ======
// Requires: M%256==0, N%256==0, K%64==0, nblocks%8==0, rows 16B-aligned.
// LDS: 2 bufs x (A 256x64 + B 256x64) bf16 = 128 KiB. 1 block/CU.
template<bool OUTBF>
__global__ __launch_bounds__(512, 2)
void gemm256(const ushort_t* __restrict__ A, const ushort_t* __restrict__ Bw,
             void* __restrict__ Cp, int M, int N, int K, int lda)
{
  __shared__ __attribute__((aligned(16))) ushort_t sm[65536];
  const int tid = threadIdx.x, lane = tid & 63, w = tid >> 6;
  const int wr = w >> 2, wc = w & 3;           // 2 x 4 waves
  const int fr = lane & 15, kq = lane >> 4;

  // XCD-aware swizzle on linear block id (nwg % 8 == 0 for all our shapes)
  const int nwg = gridDim.x, nx = N >> 8;
  const int bid = blockIdx.x;
  const int swz = (bid & 7) * (nwg >> 3) + (bid >> 3);
  const int m0 = (swz / nx) << 8, n0 = (swz % nx) << 8;

  f32x4 acc[8][4];
  #pragma unroll
  for (int m=0;m<8;m++)
    #pragma unroll
    for (int n=0;n<4;n++) acc[m][n] = (f32x4){0.f,0.f,0.f,0.f};

  // staging geometry: per K-tile 8 x gload16/thread (4 A + 4 B), LDS dest linear,
  // global source pre-swizzled chunk (rule #21 involution)
  const int srow = tid >> 3;                    // 0..63 (row within 64-row slab)
  const int gch  = (tid & 7) ^ (srow & 7);      // pre-swizzled global chunk

  auto stage = [&](int c, int kt){
    const int k0 = kt << 6;
    ushort_t* Al = sm + c*16384;
    ushort_t* Bl = sm + 32768 + c*16384;
    const ushort_t* Ag = A  + (size_t)(m0 + srow)*lda + k0 + gch*8;
    const ushort_t* Bg = Bw + (size_t)(n0 + srow)*K   + k0 + gch*8;
    #pragma unroll
    for (int i=0;i<4;i++) gload16(Ag + (size_t)(i*64)*lda, Al + i*4096 + tid*8);
    #pragma unroll
    for (int i=0;i<4;i++) gload16(Bg + (size_t)(i*64)*K,   Bl + i*4096 + tid*8);
  };

  auto compute = [&](int c){
    const ushort_t* Al = sm + c*16384;
    const ushort_t* Bl = sm + 32768 + c*16384;
    const int s = fr & 7;
    short8 bfr[4][2];
    #pragma unroll
    for (int n=0;n<4;n++){
      const int row = wc*64 + n*16 + fr;
      bfr[n][0] = *(const short8*)(Bl + row*64 + ((kq    ) ^ s)*8);
      bfr[n][1] = *(const short8*)(Bl + row*64 + ((kq + 4) ^ s)*8);
    }
    #pragma unroll
    for (int m=0;m<8;m++){
      const int row = wr*128 + m*16 + fr;
      short8 a0 = *(const short8*)(Al + row*64 + ((kq    ) ^ s)*8);
      short8 a1 = *(const short8*)(Al + row*64 + ((kq + 4) ^ s)*8);
      #pragma unroll
      for (int n=0;n<4;n++){
        acc[m][n] = __builtin_amdgcn_mfma_f32_16x16x32_bf16(a0, bfr[n][0], acc[m][n], 0,0,0);
        acc[m][n] = __builtin_amdgcn_mfma_f32_16x16x32_bf16(a1, bfr[n][1], acc[m][n], 0,0,0);
      }
    }
  };

  const int nkt = K >> 6;
  stage(0, 0);
  stage(1, 1);
  asm volatile("s_waitcnt vmcnt(8)" ::: "memory");   // buf0 resident, buf1 in flight
  __builtin_amdgcn_s_barrier();
  __builtin_amdgcn_sched_barrier(0);

  int cur = 0;
  for (int kt = 0; kt < nkt; ++kt){
    compute(cur);
    __builtin_amdgcn_s_barrier();       // all waves' ds_reads of buf cur returned
    __builtin_amdgcn_sched_barrier(0);
    if (kt + 2 < nkt){
      stage(cur, kt + 2);               // overwrite fully-consumed buffer
      asm volatile("s_waitcnt vmcnt(8)" ::: "memory");  // drain kt+1 (issued 1 tile ago)
    } else {
      asm volatile("s_waitcnt vmcnt(0)" ::: "memory");  // tail drain
    }
    __builtin_amdgcn_s_barrier();       // buf cur^1 collectively resident
    __builtin_amdgcn_sched_barrier(0);
    cur ^= 1;
  }

  const int rb = m0 + wr*128 + kq*4;
  const int cb = n0 + wc*64 + fr;
  #pragma unroll
  for (int m=0;m<8;m++)
    #pragma unroll
    for (int n=0;n<4;n++){
      const int col = cb + n*16;
      #pragma unroll
      for (int j=0;j<4;j++){
        const int row = rb + m*16 + j;
        float v = acc[m][n][j];
        if (OUTBF) ((ushort_t*)Cp)[(size_t)row*N + col] = f2bf(v);
        else       ((float*)  Cp)[(size_t)row*N + col] = v;
      }
    }
}

// ---------------- GEMM 128x128 (m97 structure) — kept for N=576 (kv_a) ----------
template<bool OUTBF>
__global__ __launch_bounds__(256)
void gemm_bt(const ushort_t* __restrict__ A, const ushort_t* __restrict__ Bw,
             void* __restrict__ Cp, int M, int N, int K, int lda)
{
  __shared__ __attribute__((aligned(16))) ushort_t As[4096];
  __shared__ __attribute__((aligned(16))) ushort_t Bs[4096];
  const int tid = threadIdx.x;
  const int lane = tid & 63;
  const int w = tid >> 6, wr = w >> 1, wc = w & 1;
  const int m0 = blockIdx.y * 128, n0 = blockIdx.x * 128;
  const int fr = lane & 15, kq = lane >> 4;

  f32x4 acc[4][4];
  #pragma unroll
  for (int i=0;i<4;i++)
    #pragma unroll
    for (int j=0;j<4;j++) acc[i][j] = (f32x4){0.f,0.f,0.f,0.f};

  const int sr = tid >> 2;
  const int scc = (tid & 3) * 8;
  const ushort_t* Ag0 = A + (size_t)(m0 + sr) * lda + scc;
  const ushort_t* Ag1 = A + (size_t)(m0 + 64 + sr) * lda + scc;
  const ushort_t* Bg0 = Bw + (size_t)(n0 + sr) * K + scc;
  const ushort_t* Bg1 = Bw + (size_t)(n0 + 64 + sr) * K + scc;
  ushort_t* Al0 = &As[tid*8];
  ushort_t* Al1 = &As[2048 + tid*8];
  ushort_t* Bl0 = &Bs[tid*8];
  ushort_t* Bl1 = &Bs[2048 + tid*8];

  for (int k0 = 0; k0 < K; k0 += 32) {
    gload16(Ag0 + k0, Al0);
    gload16(Ag1 + k0, Al1);
    gload16(Bg0 + k0, Bl0);
    gload16(Bg1 + k0, Bl1);
    __syncthreads();
    short8 a[4], b[4];
    #pragma unroll
    for (int m=0;m<4;m++) a[m] = *(const short8*)&As[(wr*64 + m*16 + fr)*32 + kq*8];
    #pragma unroll
    for (int n=0;n<4;n++) b[n] = *(const short8*)&Bs[(wc*64 + n*16 + fr)*32 + kq*8];
    #pragma unroll
    for (int m=0;m<4;m++)
      #pragma unroll
      for (int n=0;n<4;n++)
        acc[m][n] = __builtin_amdgcn_mfma_f32_16x16x32_bf16(a[m], b[n], acc[m][n], 0, 0, 0);
    __syncthreads();
  }

  const int rb = m0 + wr*64 + kq*4;
  const int cb = n0 + wc*64 + fr;
  #pragma unroll
  for (int m=0;m<4;m++)
    #pragma unroll
    for (int n=0;n<4;n++){
      int col = cb + n*16;
      if (col < N) {
        #pragma unroll
        for (int j=0;j<4;j++){
          int row = rb + m*16 + j;
          float v = acc[m][n][j];
          if (OUTBF) ((ushort_t*)Cp)[(size_t)row*N + col] = f2bf(v);
          else       ((float*)  Cp)[(size_t)row*N + col] = v;
        }
      }
    }
}

// ---------------- RMSNorm in-place on bf16 rows ----------------
__global__ __launch_bounds__(256)
void rmsnorm_ip(ushort_t* __restrict__ x, const float* __restrict__ w, int D, int rowstride){
  const int row = blockIdx.x;
  ushort_t* p = x + (size_t)row * rowstride;
  float ss = 0.f;
  for (int c = threadIdx.x*8; c < D; c += 2048) {
    short8 v = *(const short8*)(p + c);
    #pragma unroll
    for (int j=0;j<8;j++){ float f = bf2f((ushort_t)v[j]); ss += f*f; }
  }
  #pragma unroll
  for (int m=1;m<64;m<<=1) ss += __shfl_xor(ss, m, 64);
  __shared__ float red[4];
  if ((threadIdx.x & 63)==0) red[threadIdx.x>>6] = ss;
  __syncthreads();
  float tot = red[0]+red[1]+red[2]+red[3];
  float inv = rsqrtf(tot/(float)D + 1e-6f);
  for (int c = threadIdx.x*8; c < D; c += 2048) {
    short8 v = *(const short8*)(p + c);
    short8 o;
    #pragma unroll
    for (int j=0;j<8;j++) o[j] = (short)f2bf(bf2f((ushort_t)v[j]) * inv * w[c+j]);
    *(short8*)(p + c) = o;
  }
}

// ---------------- RoPE tables ----------------
__global__ void rope_tab(float* __restrict__ ct, float* __restrict__ st){
  int i = blockIdx.x*256 + threadIdx.x;
  if (i >= Sc*32) return;
  int t = i >> 5, p = i & 31;
  float invf = exp2f(-(float)p * (13.287712379549449f / 32.f)); // 10000^(-p/32)
  float ang = (float)t * invf;
  ct[i] = cosf(ang);
  st[i] = sinf(ang);
}

// RoPE on q_pe: pair (2p,2p+1) -> (a c - b s, b c + a s); layout consistent q/k
__global__ void rope_q(ushort_t* __restrict__ q, const float* __restrict__ ct, const float* __restrict__ st){
  int i = blockIdx.x*256 + threadIdx.x;
  if (i >= Bc*Sc*Hc*32) return;
  int p = i & 31, h = (i >> 5) & (Hc-1);
  int bs = i >> 10;
  int t = bs & (Sc-1);
  ushort_t* base = q + (size_t)bs*Hc*QHDc + h*QHDc + NOPEc + 2*p;
  unsigned u = *(const unsigned*)base;
  float a = bf2f((ushort_t)(u & 0xFFFFu)), bb = bf2f((ushort_t)(u >> 16));
  float c = ct[t*32+p], s = st[t*32+p];
  unsigned o = (unsigned)f2bf(a*c - bb*s) | ((unsigned)f2bf(bb*c + a*s) << 16);
  *(unsigned*)base = o;
}

__global__ void rope_k(ushort_t* __restrict__ ckv, const float* __restrict__ ct, const float* __restrict__ st){
  int i = blockIdx.x*256 + threadIdx.x;
  if (i >= Bc*Sc*32) return;
  int p = i & 31;
  int bs = i >> 5;
  int t = bs & (Sc-1);
  ushort_t* base = ckv + (size_t)bs*576 + 512 + 2*p;
  unsigned u = *(const unsigned*)base;
  float a = bf2f((ushort_t)(u & 0xFFFFu)), bb = bf2f((ushort_t)(u >> 16));
  float c = ct[t*32+p], s = st[t*32+p];
  unsigned o = (unsigned)f2bf(a*c - bb*s) | ((unsigned)f2bf(bb*c + a*s) << 16);
  *(unsigned*)base = o;
}

// ---------------- V transpose: kv[bs][h][256](+128) -> vt[bh][vd][s] ----------------
__global__ __launch_bounds__(256)
void vtrans(const ushort_t* __restrict__ kv, ushort_t* __restrict__ vt){
  const int s0 = blockIdx.x * 64;
  const int bh = blockIdx.y;
  const int batch = bh >> 5, h = bh & 31;
  __shared__ __attribute__((aligned(16))) ushort_t L[64][136];
  #pragma unroll
  for (int i = 0; i < 4; i++) {
    int chunk = i*256 + threadIdx.x;
    int r = chunk >> 4;
    int c = (chunk & 15) * 8;
    short8 v = *(const short8*)(kv + ((size_t)(batch*Sc + s0 + r)*Hc + h)*256 + 128 + c);
    *(short8*)&L[r][c] = v;
  }
  __syncthreads();
  #pragma unroll
  for (int i = 0; i < 4; i++) {
    int chunk = i*256 + threadIdx.x;
    int vd = chunk >> 3;
    int sc2 = (chunk & 7) * 8;
    short8 o;
    #pragma unroll
    for (int j=0;j<8;j++) o[j] = (short)L[sc2+j][vd];
    *(short8*)(vt + ((size_t)bh*VDc + vd)*Sc + s0 + sc2) = o;
  }
}

// ---------------- Flash attention (causal), 64 q-rows/block, 4 waves ----------------
// Grid: (x = bh [64], y = qtile [32], REVERSED). Softmax is reduction-free in the
// common path: deferred-max (speculative exp with stale row max, THR=8 in exp2
// domain) + deferred-sum (per-lane partials, one epilogue reduce).
__global__ __launch_bounds__(256)
void attn_fwd(const ushort_t* __restrict__ qb, const ushort_t* __restrict__ kvb,
              const ushort_t* __restrict__ ckv, const ushort_t* __restrict__ vt,
              ushort_t* __restrict__ out)
{
  constexpr int KP = 200, VP = 40;   // padded strides: 2-way-bank-conflict only
  __shared__ __attribute__((aligned(16))) ushort_t Ks[32*KP];
  __shared__ __attribute__((aligned(16))) ushort_t Vs[128*VP];
  __shared__ __attribute__((aligned(16))) ushort_t Ps[4][16*VP];
  const int tid = threadIdx.x, lane = tid & 63, w = tid >> 6;
  const int fr = lane & 15, kq = lane >> 4;
  const int qt = (int)gridDim.y - 1 - (int)blockIdx.y;   // long blocks first
  const int q0 = qt * 64;
  const int bh = blockIdx.x, batch = bh >> 5, h = bh & 31;

  // Q fragments in registers (rows q0 + w*16 + fr)
  const int qrow = q0 + w*16 + fr;
  const ushort_t* qptr = qb + ((size_t)(batch*Sc + qrow)*Hc + h)*QHDc;
  short8 qf[6];
  #pragma unroll
  for (int kk=0;kk<6;kk++) qf[kk] = *(const short8*)(qptr + kk*32 + kq*8);

  f32x4 acc_o[8];
  #pragma unroll
  for (int i=0;i<8;i++) acc_o[i] = (f32x4){0.f,0.f,0.f,0.f};
  float mrow[4]  = {-3e38f,-3e38f,-3e38f,-3e38f};
  float lpart[4] = {0.f,0.f,0.f,0.f};          // per-lane partial row sums
  const float scl = 0.07216878364870323f * 1.4426950408889634f; // 192^-0.5 * log2(e)
  const float THR = 8.0f;                       // defer-max threshold (exp2 domain)

  const int ktiles = q0/32 + 2;
  const int ksr = tid >> 3, ksub = tid & 7;   // K staging: 32 rows x 24 chunks
  const int vvd = tid >> 1, vsub = tid & 1;   // V staging: 128 rows x 4 chunks

  // T14 async-STAGE: global->reg for tile kt+1 issued right after first barrier,
  // reg->LDS write happens at top of next iteration (latency hides under compute).
  short8 kreg[3], vreg[2];
  const ushort_t* kbase  = kvb + ((size_t)batch*Sc + ksr)*((size_t)Hc*256) + (size_t)h*256;
  const ushort_t* pebase = ckv + ((size_t)batch*Sc + ksr)*576 + 512;
  const ushort_t* vbase  = vt + ((size_t)bh*VDc + vvd)*Sc;

  {
    // prologue: loads for kt=0
    #pragma unroll
    for (int i=0;i<3;i++){
      int c = (ksub*3 + i)*8;
      kreg[i] = (c < 128) ? *(const short8*)(kbase + c)
                          : *(const short8*)(pebase + (c - 128));
    }
    #pragma unroll
    for (int i=0;i<2;i++) vreg[i] = *(const short8*)(vbase + (vsub*2+i)*8);
  }

  for (int kt = 0; kt < ktiles; kt++) {
    const int j0 = kt*32;
    // write staged regs to LDS
    #pragma unroll
    for (int i=0;i<3;i++) *(short8*)&Ks[ksr*KP + (ksub*3 + i)*8] = kreg[i];
    #pragma unroll
    for (int i=0;i<2;i++) *(short8*)&Vs[vvd*VP + (vsub*2 + i)*8] = vreg[i];
    __syncthreads();

    // issue next tile's global loads (overlap with compute below)
    if (kt + 1 < ktiles) {
      const size_t roff = (size_t)(j0 + 32);
      #pragma unroll
      for (int i=0;i<3;i++){
        int c = (ksub*3 + i)*8;
        kreg[i] = (c < 128) ? *(const short8*)(kbase + roff*((size_t)Hc*256) + c)
                            : *(const short8*)(pebase + roff*576 + (c - 128));
      }
      #pragma unroll
      for (int i=0;i<2;i++) vreg[i] = *(const short8*)(vbase + roff + (vsub*2+i)*8);
    }

    // scores: 16 q x 32 kv (two 16-col halves)
    f32x4 s0 = (f32x4){0.f,0.f,0.f,0.f}, s1 = (f32x4){0.f,0.f,0.f,0.f};
    #pragma unroll
    for (int kk=0;kk<6;kk++){
      short8 b0 = *(const short8*)&Ks[fr*KP + kk*32 + kq*8];
      short8 b1 = *(const short8*)&Ks[(16+fr)*KP + kk*32 + kq*8];
      s0 = __builtin_amdgcn_mfma_f32_16x16x32_bf16(qf[kk], b0, s0, 0,0,0);
      s1 = __builtin_amdgcn_mfma_f32_16x16x32_bf16(qf[kk], b1, s1, 0,0,0);
    }

    const bool full = (j0 + 31 <= q0 + w*16);   // wave-uniform: no masking needed
    float x0[4], x1[4];
    int okl = 1;
    #pragma unroll
    for (int j=0;j<4;j++){
      float a  = s0[j]*scl, c2 = s1[j]*scl;
      if (!full) {
        int qp = q0 + w*16 + kq*4 + j;
        if (j0 + fr      > qp) a  = -3e38f;
        if (j0 + 16 + fr > qp) c2 = -3e38f;
      }
      x0[j] = a; x1[j] = c2;
      okl &= (fmaxf(a, c2) <= mrow[j] + THR) ? 1 : 0;
    }
    if (!__all(okl)) {
      // slow path (rare, ~first tile only): full max reduce + rescale
      float tmax[4];
      #pragma unroll
      for (int j=0;j<4;j++) tmax[j] = fmaxf(x0[j], x1[j]);
      #pragma unroll
      for (int m=1;m<16;m<<=1){
        #pragma unroll
        for (int j=0;j<4;j++) tmax[j] = fmaxf(tmax[j], __shfl_xor(tmax[j], m, 64));
      }
      #pragma unroll
      for (int j=0;j<4;j++){
        float mn = fmaxf(mrow[j], tmax[j]);
        float corr = exp2f(mrow[j] - mn);
        mrow[j] = mn;
        lpart[j] *= corr;
        #pragma unroll
        for (int i=0;i<8;i++) acc_o[i][j] *= corr;
      }
    }
    float p0[4], p1[4];
    #pragma unroll
    for (int j=0;j<4;j++){
      p0[j] = exp2f(x0[j] - mrow[j]);
      p1[j] = exp2f(x1[j] - mrow[j]);
      lpart[j] += p0[j] + p1[j];
    }
    // P -> per-wave LDS (layout [q][kv]) via packed bf16 convert
    #pragma unroll
    for (int j=0;j<4;j++){
      unsigned pk;
      asm("v_cvt_pk_bf16_f32 %0, %1, %2" : "=v"(pk) : "v"(p0[j]), "v"(p1[j]));
      Ps[w][(kq*4+j)*VP + fr]      = (ushort_t)(pk & 0xFFFFu);
      Ps[w][(kq*4+j)*VP + 16 + fr] = (ushort_t)(pk >> 16);
    }
    short8 ap = *(const short8*)&Ps[w][fr*VP + kq*8];
    #pragma unroll
    for (int v8=0; v8<8; v8++){
      short8 bv = *(const short8*)&Vs[(v8*16 + fr)*VP + kq*8];
      acc_o[v8] = __builtin_amdgcn_mfma_f32_16x16x32_bf16(ap, bv, acc_o[v8], 0,0,0);
    }
    __syncthreads();
  }

  // epilogue: one cross-lane sum reduce for the row denominators
  #pragma unroll
  for (int m=1;m<16;m<<=1){
    #pragma unroll
    for (int j=0;j<4;j++) lpart[j] += __shfl_xor(lpart[j], m, 64);
  }
  #pragma unroll
  for (int v8=0; v8<8; v8++){
    #pragma unroll
    for (int j=0;j<4;j++){
      int qg = q0 + w*16 + kq*4 + j;
      float o = acc_o[v8][j] / lpart[j];
      out[(size_t)(batch*Sc + qg)*(Hc*VDc) + h*VDc + v8*16 + fr] = f2bf(o);
    }
  }
}

// ---------------- launcher ----------------
extern "C" void kernel_launch(void* const* d_in, const int* in_sizes, int n_in,
                              void* d_out, int out_size, void* d_ws, size_t ws_size,
                              hipStream_t stream) {
  (void)in_sizes; (void)n_in; (void)out_size; (void)ws_size;
  const float* hidden  = (const float*)d_in[0];
  // d_in[1] attention_mask (pure causal -> reproduced analytically)
  // d_in[2] position_ids   (arange -> pos == s)
  const float* q_a_w   = (const float*)d_in[3];
  const float* q_a_ln  = (const float*)d_in[4];
  const float* q_b_w   = (const float*)d_in[5];
  const float* kv_a_w  = (const float*)d_in[6];
  const float* kv_a_ln = (const float*)d_in[7];
  const float* kv_b_w  = (const float*)d_in[8];
  const float* o_w     = (const float*)d_in[9];
  float* outp = (float*)d_out;

  char* ws = (char*)d_ws;
  size_t off = 0;
  auto alloc = [&](size_t n)->char*{ char* p = ws + off; off += (n + 255) & ~(size_t)255; return p; };
  ushort_t* hbf  = (ushort_t*)alloc((size_t)Bc*Sc*HIDc*2);        // hidden bf16; later reused for o_w bf16
  ushort_t* wb   = (ushort_t*)alloc((size_t)Hc*QHDc*QLRc*2);      // weight staging (max = q_b_w); covers 640-row over-read
  ushort_t* qa   = (ushort_t*)alloc((size_t)Bc*Sc*QLRc*2);
  ushort_t* qbf  = (ushort_t*)alloc((size_t)Bc*Sc*Hc*QHDc*2);
  ushort_t* ckv  = (ushort_t*)alloc((size_t)Bc*Sc*576*2);
  ushort_t* kvbf = (ushort_t*)alloc((size_t)Bc*Sc*Hc*256*2);
  ushort_t* vtb  = (ushort_t*)alloc((size_t)Bc*Hc*VDc*Sc*2);
  ushort_t* aout = (ushort_t*)alloc((size_t)Bc*Sc*Hc*VDc*2);
  float*    ct   = (float*)alloc((size_t)Sc*32*4);
  float*    st   = (float*)alloc((size_t)Sc*32*4);

  const int M = Bc*Sc; // 4096

  f32_to_bf16<<<2048,256,0,stream>>>(hidden, hbf, (long long)M*HIDc);
  // q_a = rmsnorm(hidden @ q_a_w^T)   [M=4096, N=1536, K=4096] -> 96 blocks
  f32_to_bf16<<<1024,256,0,stream>>>(q_a_w, wb, (long long)QLRc*HIDc);
  gemm256<true><<<(M/256)*(QLRc/256),512,0,stream>>>(hbf, wb, qa, M, QLRc, HIDc, HIDc);
  rmsnorm_ip<<<M,256,0,stream>>>(qa, q_a_ln, QLRc, QLRc);
  // q = q_a @ q_b_w^T   [M=4096, N=6144, K=1536] -> 384 blocks
  f32_to_bf16<<<1024,256,0,stream>>>(q_b_w, wb, (long long)Hc*QHDc*QLRc);
  gemm256<true><<<(M/256)*(Hc*QHDc/256),512,0,stream>>>(qa, wb, qbf, M, Hc*QHDc, QLRc, QLRc);
  // ckv = hidden @ kv_a_w^T   (N=576 not /256 -> old 128^2 kernel, bounds-checked)
  f32_to_bf16<<<1024,256,0,stream>>>(kv_a_w, wb, (long long)(KVLRc+ROPEc)*HIDc);
  gemm_bt<true><<<dim3(5, M/128),256,0,stream>>>(hbf, wb, ckv, M, KVLRc+ROPEc, HIDc, HIDc);
  rmsnorm_ip<<<M,256,0,stream>>>(ckv, kv_a_ln, KVLRc, 576);
  // kv = ckv_norm @ kv_b_w^T   [M=4096, N=8192, K=512, lda=576] -> 512 blocks
  f32_to_bf16<<<1024,256,0,stream>>>(kv_b_w, wb, (long long)Hc*256*KVLRc);
  gemm256<true><<<(M/256)*(Hc*256/256),512,0,stream>>>(ckv, wb, kvbf, M, Hc*256, KVLRc, 576);
  // RoPE
  rope_tab<<<CDIV(Sc*32,256),256,0,stream>>>(ct, st);
  rope_q<<<CDIV(Bc*Sc*Hc*32,256),256,0,stream>>>(qbf, ct, st);
  rope_k<<<CDIV(Bc*Sc*32,256),256,0,stream>>>(ckv, ct, st);
  // V transpose + attention (grid: x=bh for balance + L2 reuse, y=qtile reversed)
  vtrans<<<dim3(Sc/64, Bc*Hc),256,0,stream>>>(kvbf, vtb);
  attn_fwd<<<dim3(Bc*Hc, Sc/64),256,0,stream>>>(qbf, kvbf, ckv, vtb, aout);
  // out = attn @ o_w^T   [M=4096, N=4096, K=4096] -> 256 blocks, f32 store
  f32_to_bf16<<<2048,256,0,stream>>>(o_w, hbf, (long long)HIDc*HIDc);
  gemm256<false><<<(M/256)*(HIDc/256),512,0,stream>>>(aout, hbf, outp, M, HIDc, HIDc, HIDc);
}

// Round 5
// 719.625 us; speedup vs baseline: 1.5853x; 1.0583x over previous
//
#include <hip/hip_runtime.h>
#include <hip/hip_bf16.h>

typedef __attribute__((ext_vector_type(8))) short short8;
typedef __attribute__((ext_vector_type(4))) float f32x4;
typedef unsigned short ushort_t;

static constexpr int Bc = 2, Sc = 2048, HIDc = 4096, Hc = 32;
static constexpr int NOPEc = 128, ROPEc = 64, VDc = 128, QHDc = 192;
static constexpr int QLRc = 1536, KVLRc = 512;

#define CDIV(a,b) (((a)+(b)-1)/(b))

__device__ __forceinline__ float bf2f(ushort_t u){
  union { unsigned u32; float f; } x; x.u32 = ((unsigned)u) << 16; return x.f;
}
__device__ __forceinline__ ushort_t f2bf(float f){
  union { float f; unsigned u32; } x; x.f = f;
  unsigned r = x.u32 + 0x7FFFu + ((x.u32 >> 16) & 1u);
  return (ushort_t)(r >> 16);
}
__device__ __forceinline__ void gload16(const void* g, void* l){
  __builtin_amdgcn_global_load_lds((const __attribute__((address_space(1))) void*)g,
                                   (__attribute__((address_space(3))) void*)l, 16, 0, 0);
}

// ---------------- f32 -> bf16 convert (vectorized, grid-stride) ----------------
__global__ __launch_bounds__(256)
void f32_to_bf16(const float* __restrict__ in, ushort_t* __restrict__ out, long long n){
  long long stride = (long long)gridDim.x * 256 * 4;
  for (long long i = ((long long)blockIdx.x*256 + threadIdx.x)*4; i < n; i += stride){
    float4 v = *(const float4*)(in + i);
    unsigned long long pk = (unsigned long long)f2bf(v.x)
                          | ((unsigned long long)f2bf(v.y) << 16)
                          | ((unsigned long long)f2bf(v.z) << 32)
                          | ((unsigned long long)f2bf(v.w) << 48);
    *(unsigned long long*)(out + i) = pk;
  }
}

// ======== GEMM 256x256 tile, BK=64, 8 waves, dbuf LDS, swizzled, counted vmcnt ======
template<bool OUTBF>
__global__ __launch_bounds__(512, 2)
void gemm256(const ushort_t* __restrict__ A, const ushort_t* __restrict__ Bw,
             void* __restrict__ Cp, int M, int N, int K, int lda)
{
  __shared__ __attribute__((aligned(16))) ushort_t sm[65536];
  const int tid = threadIdx.x, lane = tid & 63, w = tid >> 6;
  const int wr = w >> 2, wc = w & 3;           // 2 x 4 waves
  const int fr = lane & 15, kq = lane >> 4;

  const int nwg = gridDim.x, nx = N >> 8;
  const int bid = blockIdx.x;
  const int swz = (bid & 7) * (nwg >> 3) + (bid >> 3);
  const int m0 = (swz / nx) << 8, n0 = (swz % nx) << 8;

  f32x4 acc[8][4];
  #pragma unroll
  for (int m=0;m<8;m++)
    #pragma unroll
    for (int n=0;n<4;n++) acc[m][n] = (f32x4){0.f,0.f,0.f,0.f};

  const int srow = tid >> 3;
  const int gch  = (tid & 7) ^ (srow & 7);

  auto stage = [&](int c, int kt){
    const int k0 = kt << 6;
    ushort_t* Al = sm + c*16384;
    ushort_t* Bl = sm + 32768 + c*16384;
    const ushort_t* Ag = A  + (size_t)(m0 + srow)*lda + k0 + gch*8;
    const ushort_t* Bg = Bw + (size_t)(n0 + srow)*K   + k0 + gch*8;
    #pragma unroll
    for (int i=0;i<4;i++) gload16(Ag + (size_t)(i*64)*lda, Al + i*4096 + tid*8);
    #pragma unroll
    for (int i=0;i<4;i++) gload16(Bg + (size_t)(i*64)*K,   Bl + i*4096 + tid*8);
  };

  auto compute = [&](int c){
    const ushort_t* Al = sm + c*16384;
    const ushort_t* Bl = sm + 32768 + c*16384;
    const int s = fr & 7;
    short8 bfr[4][2];
    #pragma unroll
    for (int n=0;n<4;n++){
      const int row = wc*64 + n*16 + fr;
      bfr[n][0] = *(const short8*)(Bl + row*64 + ((kq    ) ^ s)*8);
      bfr[n][1] = *(const short8*)(Bl + row*64 + ((kq + 4) ^ s)*8);
    }
    #pragma unroll
    for (int m=0;m<8;m++){
      const int row = wr*128 + m*16 + fr;
      short8 a0 = *(const short8*)(Al + row*64 + ((kq    ) ^ s)*8);
      short8 a1 = *(const short8*)(Al + row*64 + ((kq + 4) ^ s)*8);
      #pragma unroll
      for (int n=0;n<4;n++){
        acc[m][n] = __builtin_amdgcn_mfma_f32_16x16x32_bf16(a0, bfr[n][0], acc[m][n], 0,0,0);
        acc[m][n] = __builtin_amdgcn_mfma_f32_16x16x32_bf16(a1, bfr[n][1], acc[m][n], 0,0,0);
      }
    }
  };

  const int nkt = K >> 6;
  stage(0, 0);
  stage(1, 1);
  asm volatile("s_waitcnt vmcnt(8)" ::: "memory");
  __builtin_amdgcn_s_barrier();
  __builtin_amdgcn_sched_barrier(0);

  int cur = 0;
  for (int kt = 0; kt < nkt; ++kt){
    compute(cur);
    __builtin_amdgcn_s_barrier();
    __builtin_amdgcn_sched_barrier(0);
    if (kt + 2 < nkt){
      stage(cur, kt + 2);
      asm volatile("s_waitcnt vmcnt(8)" ::: "memory");
    } else {
      asm volatile("s_waitcnt vmcnt(0)" ::: "memory");
    }
    __builtin_amdgcn_s_barrier();
    __builtin_amdgcn_sched_barrier(0);
    cur ^= 1;
  }

  const int rb = m0 + wr*128 + kq*4;
  const int cb = n0 + wc*64 + fr;
  #pragma unroll
  for (int m=0;m<8;m++)
    #pragma unroll
    for (int n=0;n<4;n++){
      const int col = cb + n*16;
      #pragma unroll
      for (int j=0;j<4;j++){
        const int row = rb + m*16 + j;
        float v = acc[m][n][j];
        if (OUTBF) ((ushort_t*)Cp)[(size_t)row*N + col] = f2bf(v);
        else       ((float*)  Cp)[(size_t)row*N + col] = v;
      }
    }
}

// ======== GEMM 256x128 tile, BK=64, 8 waves (4Mx2N), dbuf, counted vmcnt ======
// For narrow-N shapes (q_a N=1536 -> 192 blocks, q_b N=6144 -> 768 blocks).
template<bool OUTBF>
__global__ __launch_bounds__(512, 2)
void gemm256x128(const ushort_t* __restrict__ A, const ushort_t* __restrict__ Bw,
                 void* __restrict__ Cp, int M, int N, int K, int lda)
{
  __shared__ __attribute__((aligned(16))) ushort_t sm[49152];   // 96 KiB
  const int tid = threadIdx.x, lane = tid & 63, w = tid >> 6;
  const int wr = w >> 1, wc = w & 1;           // 4 x 2 waves, wave tile 64x64
  const int fr = lane & 15, kq = lane >> 4;

  const int nwg = gridDim.x, nx = N >> 7;
  const int bid = blockIdx.x;
  const int swz = (bid & 7) * (nwg >> 3) + (bid >> 3);
  const int m0 = (swz / nx) << 8, n0 = (swz % nx) << 7;

  f32x4 acc[4][4];
  #pragma unroll
  for (int m=0;m<4;m++)
    #pragma unroll
    for (int n=0;n<4;n++) acc[m][n] = (f32x4){0.f,0.f,0.f,0.f};

  const int srow = tid >> 3;
  const int gch  = (tid & 7) ^ (srow & 7);

  auto stage = [&](int c, int kt){
    const int k0 = kt << 6;
    ushort_t* Al = sm + c*16384;
    ushort_t* Bl = sm + 32768 + c*8192;
    const ushort_t* Ag = A  + (size_t)(m0 + srow)*lda + k0 + gch*8;
    const ushort_t* Bg = Bw + (size_t)(n0 + srow)*K   + k0 + gch*8;
    #pragma unroll
    for (int i=0;i<4;i++) gload16(Ag + (size_t)(i*64)*lda, Al + i*4096 + tid*8);
    #pragma unroll
    for (int i=0;i<2;i++) gload16(Bg + (size_t)(i*64)*K,   Bl + i*4096 + tid*8);
  };

  auto compute = [&](int c){
    const ushort_t* Al = sm + c*16384;
    const ushort_t* Bl = sm + 32768 + c*8192;
    const int s = fr & 7;
    short8 bfr[4][2];
    #pragma unroll
    for (int n=0;n<4;n++){
      const int row = wc*64 + n*16 + fr;
      bfr[n][0] = *(const short8*)(Bl + row*64 + ((kq    ) ^ s)*8);
      bfr[n][1] = *(const short8*)(Bl + row*64 + ((kq + 4) ^ s)*8);
    }
    #pragma unroll
    for (int m=0;m<4;m++){
      const int row = wr*64 + m*16 + fr;
      short8 a0 = *(const short8*)(Al + row*64 + ((kq    ) ^ s)*8);
      short8 a1 = *(const short8*)(Al + row*64 + ((kq + 4) ^ s)*8);
      #pragma unroll
      for (int n=0;n<4;n++){
        acc[m][n] = __builtin_amdgcn_mfma_f32_16x16x32_bf16(a0, bfr[n][0], acc[m][n], 0,0,0);
        acc[m][n] = __builtin_amdgcn_mfma_f32_16x16x32_bf16(a1, bfr[n][1], acc[m][n], 0,0,0);
      }
    }
  };

  const int nkt = K >> 6;
  stage(0, 0);
  stage(1, 1);
  asm volatile("s_waitcnt vmcnt(6)" ::: "memory");
  __builtin_amdgcn_s_barrier();
  __builtin_amdgcn_sched_barrier(0);

  int cur = 0;
  for (int kt = 0; kt < nkt; ++kt){
    compute(cur);
    __builtin_amdgcn_s_barrier();
    __builtin_amdgcn_sched_barrier(0);
    if (kt + 2 < nkt){
      stage(cur, kt + 2);
      asm volatile("s_waitcnt vmcnt(6)" ::: "memory");
    } else {
      asm volatile("s_waitcnt vmcnt(0)" ::: "memory");
    }
    __builtin_amdgcn_s_barrier();
    __builtin_amdgcn_sched_barrier(0);
    cur ^= 1;
  }

  const int rb = m0 + wr*64 + kq*4;
  const int cb = n0 + wc*64 + fr;
  #pragma unroll
  for (int m=0;m<4;m++)
    #pragma unroll
    for (int n=0;n<4;n++){
      const int col = cb + n*16;
      #pragma unroll
      for (int j=0;j<4;j++){
        const int row = rb + m*16 + j;
        float v = acc[m][n][j];
        if (OUTBF) ((ushort_t*)Cp)[(size_t)row*N + col] = f2bf(v);
        else       ((float*)  Cp)[(size_t)row*N + col] = v;
      }
    }
}

// ---------------- GEMM 128x128 (m97 structure) — kept for N=576 (kv_a) ----------
template<bool OUTBF>
__global__ __launch_bounds__(256)
void gemm_bt(const ushort_t* __restrict__ A, const ushort_t* __restrict__ Bw,
             void* __restrict__ Cp, int M, int N, int K, int lda)
{
  __shared__ __attribute__((aligned(16))) ushort_t As[4096];
  __shared__ __attribute__((aligned(16))) ushort_t Bs[4096];
  const int tid = threadIdx.x;
  const int lane = tid & 63;
  const int w = tid >> 6, wr = w >> 1, wc = w & 1;
  const int m0 = blockIdx.y * 128, n0 = blockIdx.x * 128;
  const int fr = lane & 15, kq = lane >> 4;

  f32x4 acc[4][4];
  #pragma unroll
  for (int i=0;i<4;i++)
    #pragma unroll
    for (int j=0;j<4;j++) acc[i][j] = (f32x4){0.f,0.f,0.f,0.f};

  const int sr = tid >> 2;
  const int scc = (tid & 3) * 8;
  const ushort_t* Ag0 = A + (size_t)(m0 + sr) * lda + scc;
  const ushort_t* Ag1 = A + (size_t)(m0 + 64 + sr) * lda + scc;
  const ushort_t* Bg0 = Bw + (size_t)(n0 + sr) * K + scc;
  const ushort_t* Bg1 = Bw + (size_t)(n0 + 64 + sr) * K + scc;
  ushort_t* Al0 = &As[tid*8];
  ushort_t* Al1 = &As[2048 + tid*8];
  ushort_t* Bl0 = &Bs[tid*8];
  ushort_t* Bl1 = &Bs[2048 + tid*8];

  for (int k0 = 0; k0 < K; k0 += 32) {
    gload16(Ag0 + k0, Al0);
    gload16(Ag1 + k0, Al1);
    gload16(Bg0 + k0, Bl0);
    gload16(Bg1 + k0, Bl1);
    __syncthreads();
    short8 a[4], b[4];
    #pragma unroll
    for (int m=0;m<4;m++) a[m] = *(const short8*)&As[(wr*64 + m*16 + fr)*32 + kq*8];
    #pragma unroll
    for (int n=0;n<4;n++) b[n] = *(const short8*)&Bs[(wc*64 + n*16 + fr)*32 + kq*8];
    #pragma unroll
    for (int m=0;m<4;m++)
      #pragma unroll
      for (int n=0;n<4;n++)
        acc[m][n] = __builtin_amdgcn_mfma_f32_16x16x32_bf16(a[m], b[n], acc[m][n], 0, 0, 0);
    __syncthreads();
  }

  const int rb = m0 + wr*64 + kq*4;
  const int cb = n0 + wc*64 + fr;
  #pragma unroll
  for (int m=0;m<4;m++)
    #pragma unroll
    for (int n=0;n<4;n++){
      int col = cb + n*16;
      if (col < N) {
        #pragma unroll
        for (int j=0;j<4;j++){
          int row = rb + m*16 + j;
          float v = acc[m][n][j];
          if (OUTBF) ((ushort_t*)Cp)[(size_t)row*N + col] = f2bf(v);
          else       ((float*)  Cp)[(size_t)row*N + col] = v;
        }
      }
    }
}

// ---------------- RMSNorm in-place on bf16 rows ----------------
__global__ __launch_bounds__(256)
void rmsnorm_ip(ushort_t* __restrict__ x, const float* __restrict__ w, int D, int rowstride){
  const int row = blockIdx.x;
  ushort_t* p = x + (size_t)row * rowstride;
  float ss = 0.f;
  for (int c = threadIdx.x*8; c < D; c += 2048) {
    short8 v = *(const short8*)(p + c);
    #pragma unroll
    for (int j=0;j<8;j++){ float f = bf2f((ushort_t)v[j]); ss += f*f; }
  }
  #pragma unroll
  for (int m=1;m<64;m<<=1) ss += __shfl_xor(ss, m, 64);
  __shared__ float red[4];
  if ((threadIdx.x & 63)==0) red[threadIdx.x>>6] = ss;
  __syncthreads();
  float tot = red[0]+red[1]+red[2]+red[3];
  float inv = rsqrtf(tot/(float)D + 1e-6f);
  for (int c = threadIdx.x*8; c < D; c += 2048) {
    short8 v = *(const short8*)(p + c);
    short8 o;
    #pragma unroll
    for (int j=0;j<8;j++) o[j] = (short)f2bf(bf2f((ushort_t)v[j]) * inv * w[c+j]);
    *(short8*)(p + c) = o;
  }
}

// ---------------- RoPE tables ----------------
__global__ void rope_tab(float* __restrict__ ct, float* __restrict__ st){
  int i = blockIdx.x*256 + threadIdx.x;
  if (i >= Sc*32) return;
  int t = i >> 5, p = i & 31;
  float invf = exp2f(-(float)p * (13.287712379549449f / 32.f)); // 10000^(-p/32)
  float ang = (float)t * invf;
  ct[i] = cosf(ang);
  st[i] = sinf(ang);
}

// RoPE on q_pe: pair (2p,2p+1) -> (a c - b s, b c + a s); layout consistent q/k
__global__ void rope_q(ushort_t* __restrict__ q, const float* __restrict__ ct, const float* __restrict__ st){
  int i = blockIdx.x*256 + threadIdx.x;
  if (i >= Bc*Sc*Hc*32) return;
  int p = i & 31, h = (i >> 5) & (Hc-1);
  int bs = i >> 10;
  int t = bs & (Sc-1);
  ushort_t* base = q + (size_t)bs*Hc*QHDc + h*QHDc + NOPEc + 2*p;
  unsigned u = *(const unsigned*)base;
  float a = bf2f((ushort_t)(u & 0xFFFFu)), bb = bf2f((ushort_t)(u >> 16));
  float c = ct[t*32+p], s = st[t*32+p];
  unsigned o = (unsigned)f2bf(a*c - bb*s) | ((unsigned)f2bf(bb*c + a*s) << 16);
  *(unsigned*)base = o;
}

__global__ void rope_k(ushort_t* __restrict__ ckv, const float* __restrict__ ct, const float* __restrict__ st){
  int i = blockIdx.x*256 + threadIdx.x;
  if (i >= Bc*Sc*32) return;
  int p = i & 31;
  int bs = i >> 5;
  int t = bs & (Sc-1);
  ushort_t* base = ckv + (size_t)bs*576 + 512 + 2*p;
  unsigned u = *(const unsigned*)base;
  float a = bf2f((ushort_t)(u & 0xFFFFu)), bb = bf2f((ushort_t)(u >> 16));
  float c = ct[t*32+p], s = st[t*32+p];
  unsigned o = (unsigned)f2bf(a*c - bb*s) | ((unsigned)f2bf(bb*c + a*s) << 16);
  *(unsigned*)base = o;
}

// ---------------- V transpose: kv[bs][h][256](+128) -> vt[bh][vd][s] ----------------
__global__ __launch_bounds__(256)
void vtrans(const ushort_t* __restrict__ kv, ushort_t* __restrict__ vt){
  const int s0 = blockIdx.x * 64;
  const int bh = blockIdx.y;
  const int batch = bh >> 5, h = bh & 31;
  __shared__ __attribute__((aligned(16))) ushort_t L[64][136];
  #pragma unroll
  for (int i = 0; i < 4; i++) {
    int chunk = i*256 + threadIdx.x;
    int r = chunk >> 4;
    int c = (chunk & 15) * 8;
    short8 v = *(const short8*)(kv + ((size_t)(batch*Sc + s0 + r)*Hc + h)*256 + 128 + c);
    *(short8*)&L[r][c] = v;
  }
  __syncthreads();
  #pragma unroll
  for (int i = 0; i < 4; i++) {
    int chunk = i*256 + threadIdx.x;
    int vd = chunk >> 3;
    int sc2 = (chunk & 7) * 8;
    short8 o;
    #pragma unroll
    for (int j=0;j<8;j++) o[j] = (short)L[sc2+j][vd];
    *(short8*)(vt + ((size_t)bh*VDc + vd)*Sc + s0 + sc2) = o;
  }
}

// ---------------- Flash attention (causal), 4 waves ----------------
// Diagonal pairing: block (bh, y) processes q-tiles {31-y, y} sequentially ->
// every block does exactly 66 KV-tile iterations (perfect balance), and the
// whole 64x16=1024-block grid is co-resident (5 blocks/CU LDS limit).
__global__ __launch_bounds__(256)
void attn_fwd(const ushort_t* __restrict__ qb, const ushort_t* __restrict__ kvb,
              const ushort_t* __restrict__ ckv, const ushort_t* __restrict__ vt,
              ushort_t* __restrict__ out)
{
  constexpr int KP = 200, VP = 40;   // padded strides: 2-way-bank-conflict only
  __shared__ __attribute__((aligned(16))) ushort_t Ks[32*KP];
  __shared__ __attribute__((aligned(16))) ushort_t Vs[128*VP];
  __shared__ __attribute__((aligned(16))) ushort_t Ps[4][16*VP];
  const int tid = threadIdx.x, lane = tid & 63, w = tid >> 6;
  const int fr = lane & 15, kq = lane >> 4;
  const int y = (int)blockIdx.y;                      // 0..15
  const int bh = blockIdx.x, batch = bh >> 5, h = bh & 31;

  const float scl = 0.07216878364870323f * 1.4426950408889634f; // 192^-0.5 * log2(e)
  const float THR = 8.0f;

  const int ksr = tid >> 3, ksub = tid & 7;   // K staging: 32 rows x 24 chunks
  const int vvd = tid >> 1, vsub = tid & 1;   // V staging: 128 rows x 4 chunks

  const ushort_t* kbase  = kvb + ((size_t)batch*Sc + ksr)*((size_t)Hc*256) + (size_t)h*256;
  const ushort_t* pebase = ckv + ((size_t)batch*Sc + ksr)*576 + 512;
  const ushort_t* vbase  = vt + ((size_t)bh*VDc + vvd)*Sc;

  for (int seg = 0; seg < 2; ++seg) {
    const int qt = seg == 0 ? (31 - y) : y;           // heavy tile first
    const int q0 = qt * 64;

    // Q fragments in registers (rows q0 + w*16 + fr)
    const int qrow = q0 + w*16 + fr;
    const ushort_t* qptr = qb + ((size_t)(batch*Sc + qrow)*Hc + h)*QHDc;
    short8 qf[6];
    #pragma unroll
    for (int kk=0;kk<6;kk++) qf[kk] = *(const short8*)(qptr + kk*32 + kq*8);

    f32x4 acc_o[8];
    #pragma unroll
    for (int i=0;i<8;i++) acc_o[i] = (f32x4){0.f,0.f,0.f,0.f};
    float mrow[4]  = {-3e38f,-3e38f,-3e38f,-3e38f};
    float lpart[4] = {0.f,0.f,0.f,0.f};

    const int ktiles = q0/32 + 2;

    short8 kreg[3], vreg[2];
    {
      #pragma unroll
      for (int i=0;i<3;i++){
        int c = (ksub*3 + i)*8;
        kreg[i] = (c < 128) ? *(const short8*)(kbase + c)
                            : *(const short8*)(pebase + (c - 128));
      }
      #pragma unroll
      for (int i=0;i<2;i++) vreg[i] = *(const short8*)(vbase + (vsub*2+i)*8);
    }

    for (int kt = 0; kt < ktiles; kt++) {
      const int j0 = kt*32;
      #pragma unroll
      for (int i=0;i<3;i++) *(short8*)&Ks[ksr*KP + (ksub*3 + i)*8] = kreg[i];
      #pragma unroll
      for (int i=0;i<2;i++) *(short8*)&Vs[vvd*VP + (vsub*2 + i)*8] = vreg[i];
      __syncthreads();

      if (kt + 1 < ktiles) {
        const size_t roff = (size_t)(j0 + 32);
        #pragma unroll
        for (int i=0;i<3;i++){
          int c = (ksub*3 + i)*8;
          kreg[i] = (c < 128) ? *(const short8*)(kbase + roff*((size_t)Hc*256) + c)
                              : *(const short8*)(pebase + roff*576 + (c - 128));
        }
        #pragma unroll
        for (int i=0;i<2;i++) vreg[i] = *(const short8*)(vbase + roff + (vsub*2+i)*8);
      }

      f32x4 s0 = (f32x4){0.f,0.f,0.f,0.f}, s1 = (f32x4){0.f,0.f,0.f,0.f};
      __builtin_amdgcn_s_setprio(1);
      #pragma unroll
      for (int kk=0;kk<6;kk++){
        short8 b0 = *(const short8*)&Ks[fr*KP + kk*32 + kq*8];
        short8 b1 = *(const short8*)&Ks[(16+fr)*KP + kk*32 + kq*8];
        s0 = __builtin_amdgcn_mfma_f32_16x16x32_bf16(qf[kk], b0, s0, 0,0,0);
        s1 = __builtin_amdgcn_mfma_f32_16x16x32_bf16(qf[kk], b1, s1, 0,0,0);
      }
      __builtin_amdgcn_s_setprio(0);

      const bool full = (j0 + 31 <= q0 + w*16);
      float x0[4], x1[4];
      int okl = 1;
      #pragma unroll
      for (int j=0;j<4;j++){
        float a  = s0[j]*scl, c2 = s1[j]*scl;
        if (!full) {
          int qp = q0 + w*16 + kq*4 + j;
          if (j0 + fr      > qp) a  = -3e38f;
          if (j0 + 16 + fr > qp) c2 = -3e38f;
        }
        x0[j] = a; x1[j] = c2;
        okl &= (fmaxf(a, c2) <= mrow[j] + THR) ? 1 : 0;
      }
      if (!__all(okl)) {
        float tmax[4];
        #pragma unroll
        for (int j=0;j<4;j++) tmax[j] = fmaxf(x0[j], x1[j]);
        #pragma unroll
        for (int m=1;m<16;m<<=1){
          #pragma unroll
          for (int j=0;j<4;j++) tmax[j] = fmaxf(tmax[j], __shfl_xor(tmax[j], m, 64));
        }
        #pragma unroll
        for (int j=0;j<4;j++){
          float mn = fmaxf(mrow[j], tmax[j]);
          float corr = exp2f(mrow[j] - mn);
          mrow[j] = mn;
          lpart[j] *= corr;
          #pragma unroll
          for (int i=0;i<8;i++) acc_o[i][j] *= corr;
        }
      }
      float p0[4], p1[4];
      #pragma unroll
      for (int j=0;j<4;j++){
        p0[j] = exp2f(x0[j] - mrow[j]);
        p1[j] = exp2f(x1[j] - mrow[j]);
        lpart[j] += p0[j] + p1[j];
      }
      #pragma unroll
      for (int j=0;j<4;j++){
        unsigned pk;
        asm("v_cvt_pk_bf16_f32 %0, %1, %2" : "=v"(pk) : "v"(p0[j]), "v"(p1[j]));
        Ps[w][(kq*4+j)*VP + fr]      = (ushort_t)(pk & 0xFFFFu);
        Ps[w][(kq*4+j)*VP + 16 + fr] = (ushort_t)(pk >> 16);
      }
      short8 ap = *(const short8*)&Ps[w][fr*VP + kq*8];
      __builtin_amdgcn_s_setprio(1);
      #pragma unroll
      for (int v8=0; v8<8; v8++){
        short8 bv = *(const short8*)&Vs[(v8*16 + fr)*VP + kq*8];
        acc_o[v8] = __builtin_amdgcn_mfma_f32_16x16x32_bf16(ap, bv, acc_o[v8], 0,0,0);
      }
      __builtin_amdgcn_s_setprio(0);
      __syncthreads();
    }

    #pragma unroll
    for (int m=1;m<16;m<<=1){
      #pragma unroll
      for (int j=0;j<4;j++) lpart[j] += __shfl_xor(lpart[j], m, 64);
    }
    #pragma unroll
    for (int v8=0; v8<8; v8++){
      #pragma unroll
      for (int j=0;j<4;j++){
        int qg = q0 + w*16 + kq*4 + j;
        float o = acc_o[v8][j] / lpart[j];
        out[(size_t)(batch*Sc + qg)*(Hc*VDc) + h*VDc + v8*16 + fr] = f2bf(o);
      }
    }
  }
}

// ---------------- launcher ----------------
extern "C" void kernel_launch(void* const* d_in, const int* in_sizes, int n_in,
                              void* d_out, int out_size, void* d_ws, size_t ws_size,
                              hipStream_t stream) {
  (void)in_sizes; (void)n_in; (void)out_size; (void)ws_size;
  const float* hidden  = (const float*)d_in[0];
  const float* q_a_w   = (const float*)d_in[3];
  const float* q_a_ln  = (const float*)d_in[4];
  const float* q_b_w   = (const float*)d_in[5];
  const float* kv_a_w  = (const float*)d_in[6];
  const float* kv_a_ln = (const float*)d_in[7];
  const float* kv_b_w  = (const float*)d_in[8];
  const float* o_w     = (const float*)d_in[9];
  float* outp = (float*)d_out;

  char* ws = (char*)d_ws;
  size_t off = 0;
  auto alloc = [&](size_t n)->char*{ char* p = ws + off; off += (n + 255) & ~(size_t)255; return p; };
  ushort_t* hbf  = (ushort_t*)alloc((size_t)Bc*Sc*HIDc*2);
  ushort_t* wb   = (ushort_t*)alloc((size_t)Hc*QHDc*QLRc*2);
  ushort_t* qa   = (ushort_t*)alloc((size_t)Bc*Sc*QLRc*2);
  ushort_t* qbf  = (ushort_t*)alloc((size_t)Bc*Sc*Hc*QHDc*2);
  ushort_t* ckv  = (ushort_t*)alloc((size_t)Bc*Sc*576*2);
  ushort_t* kvbf = (ushort_t*)alloc((size_t)Bc*Sc*Hc*256*2);
  ushort_t* vtb  = (ushort_t*)alloc((size_t)Bc*Hc*VDc*Sc*2);
  ushort_t* aout = (ushort_t*)alloc((size_t)Bc*Sc*Hc*VDc*2);
  float*    ct   = (float*)alloc((size_t)Sc*32*4);
  float*    st   = (float*)alloc((size_t)Sc*32*4);

  const int M = Bc*Sc; // 4096

  f32_to_bf16<<<2048,256,0,stream>>>(hidden, hbf, (long long)M*HIDc);
  // q_a = rmsnorm(hidden @ q_a_w^T)   [4096,1536,4096] -> 256x128 tiles, 192 blocks
  f32_to_bf16<<<1024,256,0,stream>>>(q_a_w, wb, (long long)QLRc*HIDc);
  gemm256x128<true><<<(M/256)*(QLRc/128),512,0,stream>>>(hbf, wb, qa, M, QLRc, HIDc, HIDc);
  rmsnorm_ip<<<M,256,0,stream>>>(qa, q_a_ln, QLRc, QLRc);
  // q = q_a @ q_b_w^T   [4096,6144,1536] -> 256x128 tiles, 768 blocks (3 full rounds)
  f32_to_bf16<<<1024,256,0,stream>>>(q_b_w, wb, (long long)Hc*QHDc*QLRc);
  gemm256x128<true><<<(M/256)*(Hc*QHDc/128),512,0,stream>>>(qa, wb, qbf, M, Hc*QHDc, QLRc, QLRc);
  // ckv = hidden @ kv_a_w^T   (N=576 -> old 128^2 kernel, bounds-checked)
  f32_to_bf16<<<1024,256,0,stream>>>(kv_a_w, wb, (long long)(KVLRc+ROPEc)*HIDc);
  gemm_bt<true><<<dim3(5, M/128),256,0,stream>>>(hbf, wb, ckv, M, KVLRc+ROPEc, HIDc, HIDc);
  rmsnorm_ip<<<M,256,0,stream>>>(ckv, kv_a_ln, KVLRc, 576);
  // kv = ckv_norm @ kv_b_w^T   [4096,8192,512] -> 256^2, 512 blocks (2 full rounds)
  f32_to_bf16<<<1024,256,0,stream>>>(kv_b_w, wb, (long long)Hc*256*KVLRc);
  gemm256<true><<<(M/256)*(Hc*256/256),512,0,stream>>>(ckv, wb, kvbf, M, Hc*256, KVLRc, 576);
  // RoPE
  rope_tab<<<CDIV(Sc*32,256),256,0,stream>>>(ct, st);
  rope_q<<<CDIV(Bc*Sc*Hc*32,256),256,0,stream>>>(qbf, ct, st);
  rope_k<<<CDIV(Bc*Sc*32,256),256,0,stream>>>(ckv, ct, st);
  // V transpose + attention (diagonal-paired, 1024 uniform blocks)
  vtrans<<<dim3(Sc/64, Bc*Hc),256,0,stream>>>(kvbf, vtb);
  attn_fwd<<<dim3(Bc*Hc, 16),256,0,stream>>>(qbf, kvbf, ckv, vtb, aout);
  // out = attn @ o_w^T   [4096,4096,4096] -> 256^2, 256 blocks, f32 store
  f32_to_bf16<<<2048,256,0,stream>>>(o_w, hbf, (long long)HIDc*HIDc);
  gemm256<false><<<(M/256)*(HIDc/256),512,0,stream>>>(aout, hbf, outp, M, HIDc, HIDc, HIDc);
}